// Round 1
// baseline (827.566 us; speedup 1.0000x reference)
//
#include <hip/hip_runtime.h>
#include <cstddef>

#define QLEN   1024
#define BSZ    4
#define DMODEL 1024
#define NHEADS 16
#define SCALE  0.125f
#define LN_EPS 1e-5f

// ---------------------------------------------------------------------------
// Generic fp32 GEMM: C[m,n] = sum_k A[m,k] * B[n,k]   (A row-major, B row-major
// = "B transposed" GEMM). Tiles BM x BN x BK, 256 threads, TM x TN microtile.
// All problem dims divide tiles evenly (asserted by launch config).
// ---------------------------------------------------------------------------
template<int BM, int BN, int BK, int TM, int TN>
__global__ __launch_bounds__(256) void gemm_abt(
    const float* __restrict__ A, const float* __restrict__ B,
    float* __restrict__ C, int M, int Nn, int K, int lda, int ldb, int ldc)
{
  constexpr int SA = BM + 4;   // pad keeps banks spread; stride mult of 4 for float4
  constexpr int SB = BN + 4;
  __shared__ float As[BK][SA];
  __shared__ float Bs[BK][SB];
  const int tid = threadIdx.x;
  constexpr int TX = BN / TN;
  const int tx = tid % TX;
  const int ty = tid / TX;
  const int m0 = blockIdx.y * BM;
  const int n0 = blockIdx.x * BN;

  float acc[TM][TN];
#pragma unroll
  for (int u = 0; u < TM; ++u)
#pragma unroll
    for (int v = 0; v < TN; ++v) acc[u][v] = 0.f;

  for (int k0 = 0; k0 < K; k0 += BK) {
    constexpr int LA = BM * BK / 256;
#pragma unroll
    for (int p = 0; p < LA; ++p) {
      const int slot = tid + p * 256;
      const int kk = slot % BK, row = slot / BK;
      As[kk][row] = A[(size_t)(m0 + row) * lda + k0 + kk];
    }
    constexpr int LB = BN * BK / 256;
#pragma unroll
    for (int p = 0; p < LB; ++p) {
      const int slot = tid + p * 256;
      const int kk = slot % BK, row = slot / BK;
      Bs[kk][row] = B[(size_t)(n0 + row) * ldb + k0 + kk];
    }
    __syncthreads();
#pragma unroll
    for (int kk = 0; kk < BK; ++kk) {
      float a_frag[TM], b_frag[TN];
      if constexpr (TM % 4 == 0) {
#pragma unroll
        for (int u = 0; u < TM; u += 4) {
          const float4 t = *(const float4*)&As[kk][ty * TM + u];
          a_frag[u] = t.x; a_frag[u + 1] = t.y; a_frag[u + 2] = t.z; a_frag[u + 3] = t.w;
        }
      } else {
#pragma unroll
        for (int u = 0; u < TM; ++u) a_frag[u] = As[kk][ty * TM + u];
      }
      if constexpr (TN % 4 == 0) {
#pragma unroll
        for (int v = 0; v < TN; v += 4) {
          const float4 t = *(const float4*)&Bs[kk][tx * TN + v];
          b_frag[v] = t.x; b_frag[v + 1] = t.y; b_frag[v + 2] = t.z; b_frag[v + 3] = t.w;
        }
      } else {
#pragma unroll
        for (int v = 0; v < TN; ++v) b_frag[v] = Bs[kk][tx * TN + v];
      }
#pragma unroll
      for (int u = 0; u < TM; ++u)
#pragma unroll
        for (int v = 0; v < TN; ++v) acc[u][v] += a_frag[u] * b_frag[v];
    }
    __syncthreads();
  }

#pragma unroll
  for (int u = 0; u < TM; ++u) {
    float* crow = C + (size_t)(m0 + ty * TM + u) * ldc + n0 + tx * TN;
    if constexpr (TN % 4 == 0) {
#pragma unroll
      for (int v = 0; v < TN; v += 4) {
        float4 t; t.x = acc[u][v]; t.y = acc[u][v + 1]; t.z = acc[u][v + 2]; t.w = acc[u][v + 3];
        *(float4*)&crow[v] = t;
      }
    } else {
#pragma unroll
      for (int v = 0; v < TN; ++v) crow[v] = acc[u][v];
    }
  }
}

// ---------------------------------------------------------------------------
// AC[b,g,i,j] = sum_d (Q[i,b,g,d] + r_w_bias[g,d]) * K[j,b,g,d]
// BD[b,g,i,j] = sum_d (Q[i,b,g,d] + r_r_bias[g,d]) * R[j,g,d]
// Q/K read from w_heads ([q,b,1280]: Q at col 0, K at col 128), R from r_head_k
// grid (16,16,8)=(j-tile, i-tile, b*2+g), 64x64 tiles, K-dim 64 unrolled.
// ---------------------------------------------------------------------------
__global__ __launch_bounds__(256) void acbd_kernel(
    const float* __restrict__ wh, const float* __restrict__ rk,
    const float* __restrict__ rwb, const float* __restrict__ rrb,
    float* __restrict__ AC, float* __restrict__ BD)
{
  __shared__ float Qs[64][65], Ks[64][65], Rs[64][65];
  __shared__ float bwS[64], brS[64];
  const int tid = threadIdx.x;
  const int b = blockIdx.z >> 1, g = blockIdx.z & 1;
  const int i0 = blockIdx.y * 64, j0 = blockIdx.x * 64;

  if (tid < 64) bwS[tid] = rwb[g * 64 + tid];
  else if (tid < 128) brS[tid - 64] = rrb[g * 64 + (tid - 64)];

#pragma unroll
  for (int p = 0; p < 4; ++p) {
    const int slot = tid + p * 256;
    const int row = slot >> 4, dq = slot & 15;
    const float4 q = *(const float4*)&wh[(size_t)((i0 + row) * 4 + b) * 1280 + g * 64 + dq * 4];
    Qs[row][dq * 4 + 0] = q.x; Qs[row][dq * 4 + 1] = q.y;
    Qs[row][dq * 4 + 2] = q.z; Qs[row][dq * 4 + 3] = q.w;
    const float4 k4 = *(const float4*)&wh[(size_t)((j0 + row) * 4 + b) * 1280 + 128 + g * 64 + dq * 4];
    Ks[row][dq * 4 + 0] = k4.x; Ks[row][dq * 4 + 1] = k4.y;
    Ks[row][dq * 4 + 2] = k4.z; Ks[row][dq * 4 + 3] = k4.w;
    const float4 r4 = *(const float4*)&rk[(size_t)(j0 + row) * 128 + g * 64 + dq * 4];
    Rs[row][dq * 4 + 0] = r4.x; Rs[row][dq * 4 + 1] = r4.y;
    Rs[row][dq * 4 + 2] = r4.z; Rs[row][dq * 4 + 3] = r4.w;
  }
  __syncthreads();

  const int tx = tid & 15, ty = tid >> 4;
  float accA[4][4] = {}, accB[4][4] = {};
#pragma unroll 4
  for (int kk = 0; kk < 64; ++kk) {
    const float bw = bwS[kk], br = brS[kk];
    float qv[4], kv[4], rv[4];
#pragma unroll
    for (int u = 0; u < 4; ++u) qv[u] = Qs[ty * 4 + u][kk];
#pragma unroll
    for (int v = 0; v < 4; ++v) { kv[v] = Ks[tx * 4 + v][kk]; rv[v] = Rs[tx * 4 + v][kk]; }
#pragma unroll
    for (int u = 0; u < 4; ++u) {
      const float qw = qv[u] + bw, qr = qv[u] + br;
#pragma unroll
      for (int v = 0; v < 4; ++v) {
        accA[u][v] += qw * kv[v];
        accB[u][v] += qr * rv[v];
      }
    }
  }

  const size_t obase = (size_t)(b * 2 + g) * QLEN * QLEN;
#pragma unroll
  for (int u = 0; u < 4; ++u) {
    const size_t ro = obase + (size_t)(i0 + ty * 4 + u) * QLEN + j0 + tx * 4;
    float4 ta; ta.x = accA[u][0]; ta.y = accA[u][1]; ta.z = accA[u][2]; ta.w = accA[u][3];
    *(float4*)&AC[ro] = ta;
    float4 tb; tb.x = accB[u][0]; tb.y = accB[u][1]; tb.z = accB[u][2]; tb.w = accB[u][3];
    *(float4*)&BD[ro] = tb;
  }
}

// ---------------------------------------------------------------------------
// Fused rel-shift + mask-mix + softmax + PV.
// grid (128,16,4) = (i-tile of 8 rows, head, batch). 256 threads.
// score[i,j] = (AC[b,g,i,j] + BDshift[b,g,i,j]) * SCALE * (masks[i,j,:].mproj[:,h])
// BDshift row i = [BD[i, N-1-i .. N-1], 0, BD[i+1, 0 .. N-i-3]]  (exact ref shift)
// Softmax over j (full row in LDS), then O[r,d] = sum_j P[r,j] V[j,b,h,d].
// ---------------------------------------------------------------------------
__global__ __launch_bounds__(256) void attn_kernel(
    const float* __restrict__ AC, const float* __restrict__ BD,
    const float* __restrict__ masks, const float* __restrict__ mproj,
    const float* __restrict__ wh, float* __restrict__ av)
{
  __shared__ float S[8][1024];
  __shared__ float Vs[64][68];
  __shared__ float red[8][32];
  __shared__ float rowmax[8], rowinv[8];
  const int tid = threadIdx.x;
  const int i0 = blockIdx.x * 8;
  const int h = blockIdx.y;
  const int b = blockIdx.z;
  const int g = h >> 3;
  const float mp0 = mproj[h], mp1 = mproj[16 + h], mp2 = mproj[32 + h];

  // ---- phase 1: scores into LDS, row max ----
  const int rr = tid >> 5;     // local row 0..7
  const int jp = tid & 31;
  const int i = i0 + rr;
  const float* ACrow = AC + ((size_t)(b * 2 + g) * QLEN + i) * QLEN;
  const float* BDb = BD + (size_t)(b * 2 + g) * QLEN * QLEN;
  float tmax = -1e30f;
#pragma unroll 4
  for (int c = 0; c < 32; ++c) {
    const int j = jp + c * 32;
    float bd;
    if (j <= i)            bd = BDb[(size_t)i * QLEN + (j + QLEN - 1 - i)];
    else if (j == i + 1)   bd = 0.f;
    else                   bd = BDb[(size_t)(i + 1) * QLEN + (j - i - 2)];
    const size_t mb = ((size_t)i * QLEN + j) * 3;
    const float mw = masks[mb] * mp0 + masks[mb + 1] * mp1 + masks[mb + 2] * mp2;
    const float sc = (ACrow[j] + bd) * SCALE * mw;
    S[rr][j] = sc;
    tmax = fmaxf(tmax, sc);
  }
  red[rr][jp] = tmax;
  __syncthreads();
  if (tid < 8) {
    float m = red[tid][0];
    for (int c = 1; c < 32; ++c) m = fmaxf(m, red[tid][c]);
    rowmax[tid] = m;
  }
  __syncthreads();
  // ---- exp + row sum ----
  const float mrow = rowmax[rr];
  float psum = 0.f;
#pragma unroll 4
  for (int c = 0; c < 32; ++c) {
    const int j = jp + c * 32;
    const float e = __expf(S[rr][j] - mrow);
    S[rr][j] = e;
    psum += e;
  }
  red[rr][jp] = psum;
  __syncthreads();
  if (tid < 8) {
    float s = 0.f;
    for (int c = 0; c < 32; ++c) s += red[tid][c];
    rowinv[tid] = 1.f / s;
  }
  __syncthreads();

  // ---- phase 2: PV. 8 j-slices x (2 row-groups x 16 d-groups), 4x4 microtile
  const int sl = tid >> 5;
  const int rgrp = (tid >> 4) & 1;
  const int dgrp = tid & 15;
  const int r0 = rgrp * 4;
  float acc[4][4] = {};
  for (int jt = 0; jt < 16; ++jt) {
#pragma unroll
    for (int p = 0; p < 4; ++p) {
      const int slot = tid + p * 256;
      const int jj = slot >> 4, dq = slot & 15;
      const int j = jt * 64 + jj;
      const float4 v = *(const float4*)&wh[(size_t)(j * 4 + b) * 1280 + 256 + h * 64 + dq * 4];
      *(float4*)&Vs[jj][dq * 4] = v;
    }
    __syncthreads();
#pragma unroll
    for (int jjl = 0; jjl < 8; ++jjl) {
      const int jj = sl * 8 + jjl;
      const int j = jt * 64 + jj;
      const float4 vv = *(const float4*)&Vs[jj][dgrp * 4];
      float a_[4];
      a_[0] = S[r0 + 0][j]; a_[1] = S[r0 + 1][j];
      a_[2] = S[r0 + 2][j]; a_[3] = S[r0 + 3][j];
      float bv[4]; bv[0] = vv.x; bv[1] = vv.y; bv[2] = vv.z; bv[3] = vv.w;
#pragma unroll
      for (int u = 0; u < 4; ++u)
#pragma unroll
        for (int v = 0; v < 4; ++v) acc[u][v] += a_[u] * bv[v];
    }
    __syncthreads();   // Vs (and S, on last iter) consumed
  }

  // ---- reduce 8 j-slices (reuse S as scratch: 8*8*64 = 4096 <= 8192 floats)
  float* red2 = &S[0][0];
#pragma unroll
  for (int u = 0; u < 4; ++u) {
    float4 t; t.x = acc[u][0]; t.y = acc[u][1]; t.z = acc[u][2]; t.w = acc[u][3];
    *(float4*)&red2[(size_t)(sl * 8 + r0 + u) * 64 + dgrp * 4] = t;
  }
  __syncthreads();
  for (int o = tid; o < 512; o += 256) {
    const int rl = o >> 6, d = o & 63;
    float s = 0.f;
#pragma unroll
    for (int s8 = 0; s8 < 8; ++s8) s += red2[(size_t)(s8 * 8 + rl) * 64 + d];
    av[(size_t)((i0 + rl) * 4 + b) * 1024 + h * 64 + d] = s * rowinv[rl];
  }
}

// ---------------------------------------------------------------------------
// x = w + attn_out; post-LN. One block per (i,b) row of 1024.
// ---------------------------------------------------------------------------
__global__ __launch_bounds__(256) void ln_kernel(
    const float* __restrict__ w, const float* __restrict__ ao,
    const float* __restrict__ gamma, const float* __restrict__ beta,
    float* __restrict__ out)
{
  const int tid = threadIdx.x;
  const size_t base = (size_t)blockIdx.x * DMODEL;
  __shared__ float red[256];
  float x[4];
  float s = 0.f;
#pragma unroll
  for (int p = 0; p < 4; ++p) {
    const int c = tid + p * 256;
    x[p] = w[base + c] + ao[base + c];
    s += x[p];
  }
  red[tid] = s; __syncthreads();
  for (int off = 128; off > 0; off >>= 1) {
    if (tid < off) red[tid] += red[tid + off];
    __syncthreads();
  }
  const float mu = red[0] * (1.f / DMODEL);
  __syncthreads();
  float s2 = 0.f;
#pragma unroll
  for (int p = 0; p < 4; ++p) { const float t = x[p] - mu; s2 += t * t; }
  red[tid] = s2; __syncthreads();
  for (int off = 128; off > 0; off >>= 1) {
    if (tid < off) red[tid] += red[tid + off];
    __syncthreads();
  }
  const float rs = rsqrtf(red[0] * (1.f / DMODEL) + LN_EPS);
#pragma unroll
  for (int p = 0; p < 4; ++p) {
    const int c = tid + p * 256;
    out[base + c] = (x[p] - mu) * rs * gamma[c] + beta[c];
  }
}

// ---------------------------------------------------------------------------
extern "C" void kernel_launch(void* const* d_in, const int* in_sizes, int n_in,
                              void* d_out, int out_size, void* d_ws, size_t ws_size,
                              hipStream_t stream)
{
  const float* w     = (const float*)d_in[0];   // [1024,4,1024]
  const float* r     = (const float*)d_in[1];   // [1024,1024]
  const float* rwb   = (const float*)d_in[2];   // [2,64]
  const float* rrb   = (const float*)d_in[3];   // [2,64]
  const float* masks = (const float*)d_in[4];   // [1024,1024,3]
  const float* Wqkv  = (const float*)d_in[5];   // [1280,1024]
  const float* Wr    = (const float*)d_in[6];   // [128,1024]
  const float* mproj = (const float*)d_in[7];   // [3,16]
  const float* Wo    = (const float*)d_in[8];   // [1024,1024]
  const float* gam   = (const float*)d_in[9];   // [1024]
  const float* bet   = (const float*)d_in[10];  // [1024]
  float* out = (float*)d_out;

  float* ws = (float*)d_ws;
  float* wh = ws;                 // w_heads  [4096][1280]  = 5,242,880 f
  float* rk = wh + 5242880;       // r_head_k [1024][128]   =   131,072 f
  float* AC = rk + 131072;        // [4][2][1024][1024]     = 8,388,608 f
  float* BD = AC + 8388608;       // [4][2][1024][1024]     = 8,388,608 f
  float* av = BD + 8388608;       // attn_vec [4096][1024]  = 4,194,304 f
  float* ao = AC;                 // attn_out reuses AC (AC dead after attn)

  // 1) QKV projection: [4096,1280] = w[4096,1024] @ Wqkv[1280,1024]^T
  gemm_abt<128, 128, 16, 8, 8><<<dim3(10, 32), 256, 0, stream>>>(
      w, Wqkv, wh, 4096, 1280, 1024, 1024, 1024, 1280);
  // 2) r projection: [1024,128] = r @ Wr^T
  gemm_abt<32, 32, 16, 2, 2><<<dim3(4, 32), 256, 0, stream>>>(
      r, Wr, rk, 1024, 128, 1024, 1024, 1024, 128);
  // 3) AC / BD batched GEMMs
  acbd_kernel<<<dim3(16, 16, 8), 256, 0, stream>>>(wh, rk, rwb, rrb, AC, BD);
  // 4) rel-shift + mask mix + softmax + PV
  attn_kernel<<<dim3(128, 16, 4), 256, 0, stream>>>(AC, BD, masks, mproj, wh, av);
  // 5) output projection: attn_out = av @ Wo^T
  gemm_abt<128, 128, 16, 8, 8><<<dim3(8, 32), 256, 0, stream>>>(
      av, Wo, ao, 4096, 1024, 1024, 1024, 1024, 1024);
  // 6) residual + LayerNorm
  ln_kernel<<<4096, 256, 0, stream>>>(w, ao, gam, bet, out);
}

// Round 2
// 561.270 us; speedup vs baseline: 1.4745x; 1.4745x over previous
//
#include <hip/hip_runtime.h>
#include <cstddef>
#include <cstdint>

#define QLEN   1024
#define BSZ    4
#define DMODEL 1024
#define NHEADS 16
#define SCALE  0.125f
#define LN_EPS 1e-5f

typedef __bf16 bf16x8 __attribute__((ext_vector_type(8)));
typedef float  f32x4  __attribute__((ext_vector_type(4)));

__device__ __forceinline__ void load16_lds(const void* g, void* l) {
  __builtin_amdgcn_global_load_lds(
      (const __attribute__((address_space(1))) unsigned int*)g,
      (__attribute__((address_space(3))) unsigned int*)l, 16, 0, 0);
}

// ---------------------------------------------------------------------------
// fp32 → bf16 cast, 8 elements/thread. n must be a multiple of 2048.
// ---------------------------------------------------------------------------
__global__ __launch_bounds__(256) void cast_bf16(
    const float* __restrict__ in, __bf16* __restrict__ out)
{
  const size_t i = ((size_t)blockIdx.x * 256 + threadIdx.x) * 8;
  const float4 a = *(const float4*)&in[i];
  const float4 b = *(const float4*)&in[i + 4];
  bf16x8 o;
  o[0] = (__bf16)a.x; o[1] = (__bf16)a.y; o[2] = (__bf16)a.z; o[3] = (__bf16)a.w;
  o[4] = (__bf16)b.x; o[5] = (__bf16)b.y; o[6] = (__bf16)b.z; o[7] = (__bf16)b.w;
  *(bf16x8*)&out[i] = o;
}

// ---------------------------------------------------------------------------
// bf16 MFMA GEMM (m97 recipe): C[m,n] = sum_k A[m,k]*B[n,k], fp32 out.
// 128x128 tile, BK=32, 256 threads = 4 waves, each wave 64x64 via 4x4
// mfma_f32_16x16x32_bf16 tiles. global_load_lds 16B staging; LDS read-side
// XOR chunk rotation (slot = (chunk + row/2) & 3) to spread banks.
// M,N must be multiples of 128; K multiple of 32.
// ---------------------------------------------------------------------------
__global__ __launch_bounds__(256) void gemm_bf16(
    const __bf16* __restrict__ A, const __bf16* __restrict__ B,
    float* __restrict__ C, int K, int lda, int ldb, int ldc)
{
  __shared__ __bf16 Asl[128 * 32];
  __shared__ __bf16 Bsl[128 * 32];
  const int tid  = threadIdx.x;
  const int lane = tid & 63;
  const int wv   = tid >> 6;
  const int m0 = blockIdx.y * 128;
  const int n0 = blockIdx.x * 128;
  const int wm = (wv >> 1) * 64;
  const int wn = (wv & 1) * 64;
  const int lr = lane & 15;
  const int kq = lane >> 4;

  // staging: each wave covers rows [wv*16, wv*16+16) and +64, for A and B.
  // physical LDS dest must be waveBase + lane*16B (global_load_lds rule);
  // the XOR rotation lives on the GLOBAL side: slot s at row r holds global
  // chunk (s - (r>>1)) & 3.
  const int srow  = wv * 16 + (lane >> 2);
  const int sslot = lane & 3;
  const int sg0 = (sslot - ((srow >> 1) & 3)) & 3;
  const int sg1 = (sslot - (((srow + 64) >> 1) & 3)) & 3;
  const __bf16* Ag = A + (size_t)(m0 + srow) * lda;
  const __bf16* Bg = B + (size_t)(n0 + srow) * ldb;
  __bf16* Al = &Asl[srow * 32 + sslot * 8];
  __bf16* Bl = &Bsl[srow * 32 + sslot * 8];

  f32x4 acc[4][4];
#pragma unroll
  for (int mt = 0; mt < 4; ++mt)
#pragma unroll
    for (int nt = 0; nt < 4; ++nt)
      acc[mt][nt] = (f32x4){0.f, 0.f, 0.f, 0.f};

  for (int k0 = 0; k0 < K; k0 += 32) {
    load16_lds(Ag + k0 + sg0 * 8, Al);
    load16_lds(Ag + (size_t)64 * lda + k0 + sg1 * 8, Al + 64 * 32);
    load16_lds(Bg + k0 + sg0 * 8, Bl);
    load16_lds(Bg + (size_t)64 * ldb + k0 + sg1 * 8, Bl + 64 * 32);
    __syncthreads();

    bf16x8 af[4], bfr[4];
#pragma unroll
    for (int mt = 0; mt < 4; ++mt) {
      const int row = wm + mt * 16 + lr;
      af[mt] = *(const bf16x8*)&Asl[row * 32 + ((kq + (row >> 1)) & 3) * 8];
    }
#pragma unroll
    for (int nt = 0; nt < 4; ++nt) {
      const int row = wn + nt * 16 + lr;
      bfr[nt] = *(const bf16x8*)&Bsl[row * 32 + ((kq + (row >> 1)) & 3) * 8];
    }
#pragma unroll
    for (int mt = 0; mt < 4; ++mt)
#pragma unroll
      for (int nt = 0; nt < 4; ++nt)
        acc[mt][nt] = __builtin_amdgcn_mfma_f32_16x16x32_bf16(
            af[mt], bfr[nt], acc[mt][nt], 0, 0, 0);
    __syncthreads();
  }

  // C/D layout: col = lane&15, row = (lane>>4)*4 + reg  [m89/m91 verified]
#pragma unroll
  for (int mt = 0; mt < 4; ++mt) {
    const int row0 = m0 + wm + mt * 16 + kq * 4;
#pragma unroll
    for (int nt = 0; nt < 4; ++nt) {
      const int col = n0 + wn + nt * 16 + lr;
      const f32x4 c = acc[mt][nt];
#pragma unroll
      for (int reg = 0; reg < 4; ++reg)
        C[(size_t)(row0 + reg) * ldc + col] = c[reg];
    }
  }
}

// ---------------------------------------------------------------------------
// Generic fp32 GEMM (kept for the small r-projection): C[m,n]=sum_k A[m,k]B[n,k]
// ---------------------------------------------------------------------------
template<int BM, int BN, int BK, int TM, int TN>
__global__ __launch_bounds__(256) void gemm_abt(
    const float* __restrict__ A, const float* __restrict__ B,
    float* __restrict__ C, int M, int Nn, int K, int lda, int ldb, int ldc)
{
  constexpr int SA = BM + 4;
  constexpr int SB = BN + 4;
  __shared__ float As[BK][SA];
  __shared__ float Bs[BK][SB];
  const int tid = threadIdx.x;
  constexpr int TX = BN / TN;
  const int tx = tid % TX;
  const int ty = tid / TX;
  const int m0 = blockIdx.y * BM;
  const int n0 = blockIdx.x * BN;

  float acc[TM][TN];
#pragma unroll
  for (int u = 0; u < TM; ++u)
#pragma unroll
    for (int v = 0; v < TN; ++v) acc[u][v] = 0.f;

  for (int k0 = 0; k0 < K; k0 += BK) {
    constexpr int LA = BM * BK / 256;
#pragma unroll
    for (int p = 0; p < LA; ++p) {
      const int slot = tid + p * 256;
      const int kk = slot % BK, row = slot / BK;
      As[kk][row] = A[(size_t)(m0 + row) * lda + k0 + kk];
    }
    constexpr int LB = BN * BK / 256;
#pragma unroll
    for (int p = 0; p < LB; ++p) {
      const int slot = tid + p * 256;
      const int kk = slot % BK, row = slot / BK;
      Bs[kk][row] = B[(size_t)(n0 + row) * ldb + k0 + kk];
    }
    __syncthreads();
#pragma unroll
    for (int kk = 0; kk < BK; ++kk) {
      float a_frag[TM], b_frag[TN];
#pragma unroll
      for (int u = 0; u < TM; ++u) a_frag[u] = As[kk][ty * TM + u];
#pragma unroll
      for (int v = 0; v < TN; ++v) b_frag[v] = Bs[kk][tx * TN + v];
#pragma unroll
      for (int u = 0; u < TM; ++u)
#pragma unroll
        for (int v = 0; v < TN; ++v) acc[u][v] += a_frag[u] * b_frag[v];
    }
    __syncthreads();
  }

#pragma unroll
  for (int u = 0; u < TM; ++u) {
    float* crow = C + (size_t)(m0 + ty * TM + u) * ldc + n0 + tx * TN;
#pragma unroll
    for (int v = 0; v < TN; ++v) crow[v] = acc[u][v];
  }
}

// ---------------------------------------------------------------------------
// AC/BD batched GEMMs (unchanged from round 1)
// ---------------------------------------------------------------------------
__global__ __launch_bounds__(256) void acbd_kernel(
    const float* __restrict__ wh, const float* __restrict__ rk,
    const float* __restrict__ rwb, const float* __restrict__ rrb,
    float* __restrict__ AC, float* __restrict__ BD)
{
  __shared__ float Qs[64][65], Ks[64][65], Rs[64][65];
  __shared__ float bwS[64], brS[64];
  const int tid = threadIdx.x;
  const int b = blockIdx.z >> 1, g = blockIdx.z & 1;
  const int i0 = blockIdx.y * 64, j0 = blockIdx.x * 64;

  if (tid < 64) bwS[tid] = rwb[g * 64 + tid];
  else if (tid < 128) brS[tid - 64] = rrb[g * 64 + (tid - 64)];

#pragma unroll
  for (int p = 0; p < 4; ++p) {
    const int slot = tid + p * 256;
    const int row = slot >> 4, dq = slot & 15;
    const float4 q = *(const float4*)&wh[(size_t)((i0 + row) * 4 + b) * 1280 + g * 64 + dq * 4];
    Qs[row][dq * 4 + 0] = q.x; Qs[row][dq * 4 + 1] = q.y;
    Qs[row][dq * 4 + 2] = q.z; Qs[row][dq * 4 + 3] = q.w;
    const float4 k4 = *(const float4*)&wh[(size_t)((j0 + row) * 4 + b) * 1280 + 128 + g * 64 + dq * 4];
    Ks[row][dq * 4 + 0] = k4.x; Ks[row][dq * 4 + 1] = k4.y;
    Ks[row][dq * 4 + 2] = k4.z; Ks[row][dq * 4 + 3] = k4.w;
    const float4 r4 = *(const float4*)&rk[(size_t)(j0 + row) * 128 + g * 64 + dq * 4];
    Rs[row][dq * 4 + 0] = r4.x; Rs[row][dq * 4 + 1] = r4.y;
    Rs[row][dq * 4 + 2] = r4.z; Rs[row][dq * 4 + 3] = r4.w;
  }
  __syncthreads();

  const int tx = tid & 15, ty = tid >> 4;
  float accA[4][4] = {}, accB[4][4] = {};
#pragma unroll 4
  for (int kk = 0; kk < 64; ++kk) {
    const float bw = bwS[kk], br = brS[kk];
    float qv[4], kv[4], rv[4];
#pragma unroll
    for (int u = 0; u < 4; ++u) qv[u] = Qs[ty * 4 + u][kk];
#pragma unroll
    for (int v = 0; v < 4; ++v) { kv[v] = Ks[tx * 4 + v][kk]; rv[v] = Rs[tx * 4 + v][kk]; }
#pragma unroll
    for (int u = 0; u < 4; ++u) {
      const float qw = qv[u] + bw, qr = qv[u] + br;
#pragma unroll
      for (int v = 0; v < 4; ++v) {
        accA[u][v] += qw * kv[v];
        accB[u][v] += qr * rv[v];
      }
    }
  }

  const size_t obase = (size_t)(b * 2 + g) * QLEN * QLEN;
#pragma unroll
  for (int u = 0; u < 4; ++u) {
    const size_t ro = obase + (size_t)(i0 + ty * 4 + u) * QLEN + j0 + tx * 4;
    float4 ta; ta.x = accA[u][0]; ta.y = accA[u][1]; ta.z = accA[u][2]; ta.w = accA[u][3];
    *(float4*)&AC[ro] = ta;
    float4 tb; tb.x = accB[u][0]; tb.y = accB[u][1]; tb.z = accB[u][2]; tb.w = accB[u][3];
    *(float4*)&BD[ro] = tb;
  }
}

// ---------------------------------------------------------------------------
// Fused rel-shift + mask-mix + softmax + PV (round-1 version, now emits bf16)
// ---------------------------------------------------------------------------
__global__ __launch_bounds__(256) void attn_kernel(
    const float* __restrict__ AC, const float* __restrict__ BD,
    const float* __restrict__ masks, const float* __restrict__ mproj,
    const float* __restrict__ wh, __bf16* __restrict__ av)
{
  __shared__ float S[8][1024];
  __shared__ float Vs[64][68];
  __shared__ float red[8][32];
  __shared__ float rowmax[8], rowinv[8];
  const int tid = threadIdx.x;
  const int i0 = blockIdx.x * 8;
  const int h = blockIdx.y;
  const int b = blockIdx.z;
  const int g = h >> 3;
  const float mp0 = mproj[h], mp1 = mproj[16 + h], mp2 = mproj[32 + h];

  const int rr = tid >> 5;
  const int jp = tid & 31;
  const int i = i0 + rr;
  const float* ACrow = AC + ((size_t)(b * 2 + g) * QLEN + i) * QLEN;
  const float* BDb = BD + (size_t)(b * 2 + g) * QLEN * QLEN;
  float tmax = -1e30f;
#pragma unroll 4
  for (int c = 0; c < 32; ++c) {
    const int j = jp + c * 32;
    float bd;
    if (j <= i)            bd = BDb[(size_t)i * QLEN + (j + QLEN - 1 - i)];
    else if (j == i + 1)   bd = 0.f;
    else                   bd = BDb[(size_t)(i + 1) * QLEN + (j - i - 2)];
    const size_t mb = ((size_t)i * QLEN + j) * 3;
    const float mw = masks[mb] * mp0 + masks[mb + 1] * mp1 + masks[mb + 2] * mp2;
    const float sc = (ACrow[j] + bd) * SCALE * mw;
    S[rr][j] = sc;
    tmax = fmaxf(tmax, sc);
  }
  red[rr][jp] = tmax;
  __syncthreads();
  if (tid < 8) {
    float m = red[tid][0];
    for (int c = 1; c < 32; ++c) m = fmaxf(m, red[tid][c]);
    rowmax[tid] = m;
  }
  __syncthreads();
  const float mrow = rowmax[rr];
  float psum = 0.f;
#pragma unroll 4
  for (int c = 0; c < 32; ++c) {
    const int j = jp + c * 32;
    const float e = __expf(S[rr][j] - mrow);
    S[rr][j] = e;
    psum += e;
  }
  red[rr][jp] = psum;
  __syncthreads();
  if (tid < 8) {
    float s = 0.f;
    for (int c = 0; c < 32; ++c) s += red[tid][c];
    rowinv[tid] = 1.f / s;
  }
  __syncthreads();

  const int sl = tid >> 5;
  const int rgrp = (tid >> 4) & 1;
  const int dgrp = tid & 15;
  const int r0 = rgrp * 4;
  float acc[4][4] = {};
  for (int jt = 0; jt < 16; ++jt) {
#pragma unroll
    for (int p = 0; p < 4; ++p) {
      const int slot = tid + p * 256;
      const int jj = slot >> 4, dq = slot & 15;
      const int j = jt * 64 + jj;
      const float4 v = *(const float4*)&wh[(size_t)(j * 4 + b) * 1280 + 256 + h * 64 + dq * 4];
      *(float4*)&Vs[jj][dq * 4] = v;
    }
    __syncthreads();
#pragma unroll
    for (int jjl = 0; jjl < 8; ++jjl) {
      const int jj = sl * 8 + jjl;
      const int j = jt * 64 + jj;
      const float4 vv = *(const float4*)&Vs[jj][dgrp * 4];
      float a_[4];
      a_[0] = S[r0 + 0][j]; a_[1] = S[r0 + 1][j];
      a_[2] = S[r0 + 2][j]; a_[3] = S[r0 + 3][j];
      float bv[4]; bv[0] = vv.x; bv[1] = vv.y; bv[2] = vv.z; bv[3] = vv.w;
#pragma unroll
      for (int u = 0; u < 4; ++u)
#pragma unroll
        for (int v = 0; v < 4; ++v) acc[u][v] += a_[u] * bv[v];
    }
    __syncthreads();
  }

  float* red2 = &S[0][0];
#pragma unroll
  for (int u = 0; u < 4; ++u) {
    float4 t; t.x = acc[u][0]; t.y = acc[u][1]; t.z = acc[u][2]; t.w = acc[u][3];
    *(float4*)&red2[(size_t)(sl * 8 + r0 + u) * 64 + dgrp * 4] = t;
  }
  __syncthreads();
  for (int o = tid; o < 512; o += 256) {
    const int rl = o >> 6, d = o & 63;
    float s = 0.f;
#pragma unroll
    for (int s8 = 0; s8 < 8; ++s8) s += red2[(size_t)(s8 * 8 + rl) * 64 + d];
    av[(size_t)((i0 + rl) * 4 + b) * 1024 + h * 64 + d] = (__bf16)(s * rowinv[rl]);
  }
}

// ---------------------------------------------------------------------------
// residual + LayerNorm (unchanged)
// ---------------------------------------------------------------------------
__global__ __launch_bounds__(256) void ln_kernel(
    const float* __restrict__ w, const float* __restrict__ ao,
    const float* __restrict__ gamma, const float* __restrict__ beta,
    float* __restrict__ out)
{
  const int tid = threadIdx.x;
  const size_t base = (size_t)blockIdx.x * DMODEL;
  __shared__ float red[256];
  float x[4];
  float s = 0.f;
#pragma unroll
  for (int p = 0; p < 4; ++p) {
    const int c = tid + p * 256;
    x[p] = w[base + c] + ao[base + c];
    s += x[p];
  }
  red[tid] = s; __syncthreads();
  for (int off = 128; off > 0; off >>= 1) {
    if (tid < off) red[tid] += red[tid + off];
    __syncthreads();
  }
  const float mu = red[0] * (1.f / DMODEL);
  __syncthreads();
  float s2 = 0.f;
#pragma unroll
  for (int p = 0; p < 4; ++p) { const float t = x[p] - mu; s2 += t * t; }
  red[tid] = s2; __syncthreads();
  for (int off = 128; off > 0; off >>= 1) {
    if (tid < off) red[tid] += red[tid + off];
    __syncthreads();
  }
  const float rs = rsqrtf(red[0] * (1.f / DMODEL) + LN_EPS);
#pragma unroll
  for (int p = 0; p < 4; ++p) {
    const int c = tid + p * 256;
    out[base + c] = (x[p] - mu) * rs * gamma[c] + beta[c];
  }
}

// ---------------------------------------------------------------------------
extern "C" void kernel_launch(void* const* d_in, const int* in_sizes, int n_in,
                              void* d_out, int out_size, void* d_ws, size_t ws_size,
                              hipStream_t stream)
{
  const float* w     = (const float*)d_in[0];
  const float* r     = (const float*)d_in[1];
  const float* rwb   = (const float*)d_in[2];
  const float* rrb   = (const float*)d_in[3];
  const float* masks = (const float*)d_in[4];
  const float* Wqkv  = (const float*)d_in[5];
  const float* Wr    = (const float*)d_in[6];
  const float* mproj = (const float*)d_in[7];
  const float* Wo    = (const float*)d_in[8];
  const float* gam   = (const float*)d_in[9];
  const float* bet   = (const float*)d_in[10];
  float* out = (float*)d_out;

  float* ws = (float*)d_ws;
  float* wh = ws;                 // w_heads  [4096][1280]
  float* rk = wh + 5242880;       // r_head_k [1024][128]
  float* AC = rk + 131072;        // [4*2][1024][1024]
  float* BD = AC + 8388608;       // [4*2][1024][1024]
  float* av = BD + 8388608;       // attn_vec, used as bf16 [4096][1024]
  float* ao = AC;                 // attn_out reuses AC

  // bf16 overlays inside the (temporarily dead) BD region:
  __bf16* w_bf    = (__bf16*)BD;                       // 4,194,304 elts
  __bf16* Wqkv_bf = (__bf16*)(BD + 2097152);           // 1,310,720 elts
  __bf16* Wo_bf   = (__bf16*)BD;                       // 1,048,576 elts (after attn)
  __bf16* av_bf   = (__bf16*)av;

  // 1) casts for QKV gemm (BD region not yet live)
  cast_bf16<<<2048, 256, 0, stream>>>(w, w_bf);
  cast_bf16<<<640, 256, 0, stream>>>(Wqkv, Wqkv_bf);
  // 2) QKV projection (bf16 MFMA): [4096,1280] = w @ Wqkv^T
  gemm_bf16<<<dim3(10, 32), 256, 0, stream>>>(w_bf, Wqkv_bf, wh, 1024, 1024, 1024, 1280);
  // 3) r projection (small, fp32)
  gemm_abt<32, 32, 16, 2, 2><<<dim3(4, 32), 256, 0, stream>>>(
      r, Wr, rk, 1024, 128, 1024, 1024, 1024, 128);
  // 4) AC / BD batched GEMMs (clobbers w_bf/Wqkv_bf — dead)
  acbd_kernel<<<dim3(16, 16, 8), 256, 0, stream>>>(wh, rk, rwb, rrb, AC, BD);
  // 5) rel-shift + mask mix + softmax + PV → av (bf16)
  attn_kernel<<<dim3(128, 16, 4), 256, 0, stream>>>(AC, BD, masks, mproj, wh, av_bf);
  // 6) cast Wo (BD dead now), then output projection (bf16 MFMA)
  cast_bf16<<<512, 256, 0, stream>>>(Wo, Wo_bf);
  gemm_bf16<<<dim3(8, 32), 256, 0, stream>>>(av_bf, Wo_bf, ao, 1024, 1024, 1024, 1024);
  // 7) residual + LayerNorm
  ln_kernel<<<4096, 256, 0, stream>>>(w, ao, gam, bet, out);
}

// Round 3
// 476.016 us; speedup vs baseline: 1.7385x; 1.1791x over previous
//
#include <hip/hip_runtime.h>
#include <cstddef>
#include <cstdint>

#define QLEN   1024
#define BSZ    4
#define DMODEL 1024
#define NHEADS 16
#define SCALE  0.125f
#define LN_EPS 1e-5f

typedef __bf16 bf16x8 __attribute__((ext_vector_type(8)));
typedef __bf16 bf16x4 __attribute__((ext_vector_type(4)));
typedef float  f32x4  __attribute__((ext_vector_type(4)));

__device__ __forceinline__ void load16_lds(const void* g, void* l) {
  __builtin_amdgcn_global_load_lds(
      (const __attribute__((address_space(1))) unsigned int*)g,
      (__attribute__((address_space(3))) unsigned int*)l, 16, 0, 0);
}

// ---------------------------------------------------------------------------
// fp32 -> bf16 cast, 8 elements/thread.
// ---------------------------------------------------------------------------
__global__ __launch_bounds__(256) void cast_bf16(
    const float* __restrict__ in, __bf16* __restrict__ out)
{
  const size_t i = ((size_t)blockIdx.x * 256 + threadIdx.x) * 8;
  const float4 a = *(const float4*)&in[i];
  const float4 b = *(const float4*)&in[i + 4];
  bf16x8 o;
  o[0] = (__bf16)a.x; o[1] = (__bf16)a.y; o[2] = (__bf16)a.z; o[3] = (__bf16)a.w;
  o[4] = (__bf16)b.x; o[5] = (__bf16)b.y; o[6] = (__bf16)b.z; o[7] = (__bf16)b.w;
  *(bf16x8*)&out[i] = o;
}

// ---------------------------------------------------------------------------
// V transpose+cast: wh fp32 [(j*4+b)*1280 + 256 + h*64 + d]  ->
// Vt bf16 [((b*16+h)*64 + d)*1024 + j].  grid (jt=16, bh=64), 256 thr.
// ---------------------------------------------------------------------------
__global__ __launch_bounds__(256) void vt_cast(
    const float* __restrict__ wh, __bf16* __restrict__ Vt)
{
  __shared__ float tile[64][65];
  const int tid = threadIdx.x;
  const int jt = blockIdx.x, bh = blockIdx.y;
  const int b = bh >> 4, h = bh & 15;
#pragma unroll
  for (int p = 0; p < 16; ++p) {
    const int idx = p * 256 + tid;
    const int jj = idx >> 6, dd = idx & 63;
    tile[jj][dd] = wh[(size_t)((jt * 64 + jj) * 4 + b) * 1280 + 256 + h * 64 + dd];
  }
  __syncthreads();
#pragma unroll
  for (int p = 0; p < 16; ++p) {
    const int idx = p * 256 + tid;
    const int dd = idx >> 6, jj = idx & 63;
    Vt[((size_t)(bh * 64 + dd)) * 1024 + jt * 64 + jj] = (__bf16)tile[jj][dd];
  }
}

// ---------------------------------------------------------------------------
// masks [1024*1024][3] fp32 -> 3 planar bf16 planes of 1048576.
// ---------------------------------------------------------------------------
__global__ __launch_bounds__(256) void cast_masks(
    const float* __restrict__ masks, __bf16* __restrict__ mp)
{
  const size_t ij0 = ((size_t)blockIdx.x * 256 + threadIdx.x) * 4;
  const float4 a = *(const float4*)&masks[ij0 * 3];
  const float4 b = *(const float4*)&masks[ij0 * 3 + 4];
  const float4 c = *(const float4*)&masks[ij0 * 3 + 8];
  bf16x4 p0, p1, p2;
  p0[0] = (__bf16)a.x; p0[1] = (__bf16)a.w; p0[2] = (__bf16)b.z; p0[3] = (__bf16)c.y;
  p1[0] = (__bf16)a.y; p1[1] = (__bf16)b.x; p1[2] = (__bf16)b.w; p1[3] = (__bf16)c.z;
  p2[0] = (__bf16)a.z; p2[1] = (__bf16)b.y; p2[2] = (__bf16)c.x; p2[3] = (__bf16)c.w;
  *(bf16x4*)&mp[ij0]           = p0;
  *(bf16x4*)&mp[1048576 + ij0] = p1;
  *(bf16x4*)&mp[2097152 + ij0] = p2;
}

// ---------------------------------------------------------------------------
// bf16 MFMA GEMM (m97 recipe), unchanged from round 2.
// ---------------------------------------------------------------------------
__global__ __launch_bounds__(256) void gemm_bf16(
    const __bf16* __restrict__ A, const __bf16* __restrict__ B,
    float* __restrict__ C, int K, int lda, int ldb, int ldc)
{
  __shared__ __bf16 Asl[128 * 32];
  __shared__ __bf16 Bsl[128 * 32];
  const int tid  = threadIdx.x;
  const int lane = tid & 63;
  const int wv   = tid >> 6;
  const int m0 = blockIdx.y * 128;
  const int n0 = blockIdx.x * 128;
  const int wm = (wv >> 1) * 64;
  const int wn = (wv & 1) * 64;
  const int lr = lane & 15;
  const int kq = lane >> 4;

  const int srow  = wv * 16 + (lane >> 2);
  const int sslot = lane & 3;
  const int sg0 = (sslot - ((srow >> 1) & 3)) & 3;
  const int sg1 = (sslot - (((srow + 64) >> 1) & 3)) & 3;
  const __bf16* Ag = A + (size_t)(m0 + srow) * lda;
  const __bf16* Bg = B + (size_t)(n0 + srow) * ldb;
  __bf16* Al = &Asl[srow * 32 + sslot * 8];
  __bf16* Bl = &Bsl[srow * 32 + sslot * 8];

  f32x4 acc[4][4];
#pragma unroll
  for (int mt = 0; mt < 4; ++mt)
#pragma unroll
    for (int nt = 0; nt < 4; ++nt)
      acc[mt][nt] = (f32x4){0.f, 0.f, 0.f, 0.f};

  for (int k0 = 0; k0 < K; k0 += 32) {
    load16_lds(Ag + k0 + sg0 * 8, Al);
    load16_lds(Ag + (size_t)64 * lda + k0 + sg1 * 8, Al + 64 * 32);
    load16_lds(Bg + k0 + sg0 * 8, Bl);
    load16_lds(Bg + (size_t)64 * ldb + k0 + sg1 * 8, Bl + 64 * 32);
    __syncthreads();

    bf16x8 af[4], bfr[4];
#pragma unroll
    for (int mt = 0; mt < 4; ++mt) {
      const int row = wm + mt * 16 + lr;
      af[mt] = *(const bf16x8*)&Asl[row * 32 + ((kq + (row >> 1)) & 3) * 8];
    }
#pragma unroll
    for (int nt = 0; nt < 4; ++nt) {
      const int row = wn + nt * 16 + lr;
      bfr[nt] = *(const bf16x8*)&Bsl[row * 32 + ((kq + (row >> 1)) & 3) * 8];
    }
#pragma unroll
    for (int mt = 0; mt < 4; ++mt)
#pragma unroll
      for (int nt = 0; nt < 4; ++nt)
        acc[mt][nt] = __builtin_amdgcn_mfma_f32_16x16x32_bf16(
            af[mt], bfr[nt], acc[mt][nt], 0, 0, 0);
    __syncthreads();
  }

#pragma unroll
  for (int mt = 0; mt < 4; ++mt) {
    const int row0 = m0 + wm + mt * 16 + kq * 4;
#pragma unroll
    for (int nt = 0; nt < 4; ++nt) {
      const int col = n0 + wn + nt * 16 + lr;
      const f32x4 c = acc[mt][nt];
#pragma unroll
      for (int reg = 0; reg < 4; ++reg)
        C[(size_t)(row0 + reg) * ldc + col] = c[reg];
    }
  }
}

// ---------------------------------------------------------------------------
// Generic fp32 GEMM (small r-projection only).
// ---------------------------------------------------------------------------
template<int BM, int BN, int BK, int TM, int TN>
__global__ __launch_bounds__(256) void gemm_abt(
    const float* __restrict__ A, const float* __restrict__ B,
    float* __restrict__ C, int M, int Nn, int K, int lda, int ldb, int ldc)
{
  constexpr int SA = BM + 4;
  constexpr int SB = BN + 4;
  __shared__ float As[BK][SA];
  __shared__ float Bs[BK][SB];
  const int tid = threadIdx.x;
  constexpr int TX = BN / TN;
  const int tx = tid % TX;
  const int ty = tid / TX;
  const int m0 = blockIdx.y * BM;
  const int n0 = blockIdx.x * BN;

  float acc[TM][TN];
#pragma unroll
  for (int u = 0; u < TM; ++u)
#pragma unroll
    for (int v = 0; v < TN; ++v) acc[u][v] = 0.f;

  for (int k0 = 0; k0 < K; k0 += BK) {
    constexpr int LA = BM * BK / 256;
#pragma unroll
    for (int p = 0; p < LA; ++p) {
      const int slot = tid + p * 256;
      const int kk = slot % BK, row = slot / BK;
      As[kk][row] = A[(size_t)(m0 + row) * lda + k0 + kk];
    }
    constexpr int LB = BN * BK / 256;
#pragma unroll
    for (int p = 0; p < LB; ++p) {
      const int slot = tid + p * 256;
      const int kk = slot % BK, row = slot / BK;
      Bs[kk][row] = B[(size_t)(n0 + row) * ldb + k0 + kk];
    }
    __syncthreads();
#pragma unroll
    for (int kk = 0; kk < BK; ++kk) {
      float a_frag[TM], b_frag[TN];
#pragma unroll
      for (int u = 0; u < TM; ++u) a_frag[u] = As[kk][ty * TM + u];
#pragma unroll
      for (int v = 0; v < TN; ++v) b_frag[v] = Bs[kk][tx * TN + v];
#pragma unroll
      for (int u = 0; u < TM; ++u)
#pragma unroll
        for (int v = 0; v < TN; ++v) acc[u][v] += a_frag[u] * b_frag[v];
    }
    __syncthreads();
  }

#pragma unroll
  for (int u = 0; u < TM; ++u) {
    float* crow = C + (size_t)(m0 + ty * TM + u) * ldc + n0 + tx * TN;
#pragma unroll
    for (int v = 0; v < TN; ++v) crow[v] = acc[u][v];
  }
}

// ---------------------------------------------------------------------------
// AC/BD batched GEMMs (unchanged).
// ---------------------------------------------------------------------------
__global__ __launch_bounds__(256) void acbd_kernel(
    const float* __restrict__ wh, const float* __restrict__ rk,
    const float* __restrict__ rwb, const float* __restrict__ rrb,
    float* __restrict__ AC, float* __restrict__ BD)
{
  __shared__ float Qs[64][65], Ks[64][65], Rs[64][65];
  __shared__ float bwS[64], brS[64];
  const int tid = threadIdx.x;
  const int b = blockIdx.z >> 1, g = blockIdx.z & 1;
  const int i0 = blockIdx.y * 64, j0 = blockIdx.x * 64;

  if (tid < 64) bwS[tid] = rwb[g * 64 + tid];
  else if (tid < 128) brS[tid - 64] = rrb[g * 64 + (tid - 64)];

#pragma unroll
  for (int p = 0; p < 4; ++p) {
    const int slot = tid + p * 256;
    const int row = slot >> 4, dq = slot & 15;
    const float4 q = *(const float4*)&wh[(size_t)((i0 + row) * 4 + b) * 1280 + g * 64 + dq * 4];
    Qs[row][dq * 4 + 0] = q.x; Qs[row][dq * 4 + 1] = q.y;
    Qs[row][dq * 4 + 2] = q.z; Qs[row][dq * 4 + 3] = q.w;
    const float4 k4 = *(const float4*)&wh[(size_t)((j0 + row) * 4 + b) * 1280 + 128 + g * 64 + dq * 4];
    Ks[row][dq * 4 + 0] = k4.x; Ks[row][dq * 4 + 1] = k4.y;
    Ks[row][dq * 4 + 2] = k4.z; Ks[row][dq * 4 + 3] = k4.w;
    const float4 r4 = *(const float4*)&rk[(size_t)(j0 + row) * 128 + g * 64 + dq * 4];
    Rs[row][dq * 4 + 0] = r4.x; Rs[row][dq * 4 + 1] = r4.y;
    Rs[row][dq * 4 + 2] = r4.z; Rs[row][dq * 4 + 3] = r4.w;
  }
  __syncthreads();

  const int tx = tid & 15, ty = tid >> 4;
  float accA[4][4] = {}, accB[4][4] = {};
#pragma unroll 4
  for (int kk = 0; kk < 64; ++kk) {
    const float bw = bwS[kk], br = brS[kk];
    float qv[4], kv[4], rv[4];
#pragma unroll
    for (int u = 0; u < 4; ++u) qv[u] = Qs[ty * 4 + u][kk];
#pragma unroll
    for (int v = 0; v < 4; ++v) { kv[v] = Ks[tx * 4 + v][kk]; rv[v] = Rs[tx * 4 + v][kk]; }
#pragma unroll
    for (int u = 0; u < 4; ++u) {
      const float qw = qv[u] + bw, qr = qv[u] + br;
#pragma unroll
      for (int v = 0; v < 4; ++v) {
        accA[u][v] += qw * kv[v];
        accB[u][v] += qr * rv[v];
      }
    }
  }

  const size_t obase = (size_t)(b * 2 + g) * QLEN * QLEN;
#pragma unroll
  for (int u = 0; u < 4; ++u) {
    const size_t ro = obase + (size_t)(i0 + ty * 4 + u) * QLEN + j0 + tx * 4;
    float4 ta; ta.x = accA[u][0]; ta.y = accA[u][1]; ta.z = accA[u][2]; ta.w = accA[u][3];
    *(float4*)&AC[ro] = ta;
    float4 tb; tb.x = accB[u][0]; tb.y = accB[u][1]; tb.z = accB[u][2]; tb.w = accB[u][3];
    *(float4*)&BD[ro] = tb;
  }
}

// ---------------------------------------------------------------------------
// attn2: one block = 16 rows x one (g,b), loops over the group's 8 heads.
// Phase A: T = (AC + BDshift)*SCALE -> bf16 LDS (shared by 8 heads).
// Per head: scores = T * maskmix -> P (bf16, XOR-swizzled), softmax with
// 16-lane shuffle reductions, P pre-scaled by 1/rowsum, then PV on MFMA
// (A = P from LDS, B = Vt rows loaded global->VGPR; no V staging barriers).
// Grid (64, 2, 4), 256 threads. LDS = exactly 64 KB -> 2 blocks/CU.
// ---------------------------------------------------------------------------
__global__ __launch_bounds__(256) void attn2(
    const float* __restrict__ AC, const float* __restrict__ BD,
    const __bf16* __restrict__ masksP, const float* __restrict__ mproj,
    const __bf16* __restrict__ Vt, __bf16* __restrict__ av)
{
  __shared__ __bf16 T[16 * 1024];
  __shared__ __bf16 P[16 * 1024];
  const int tid = threadIdx.x;
  const int i0 = blockIdx.x * 16;
  const int g = blockIdx.y, b = blockIdx.z;
  const size_t bg = (size_t)(b * 2 + g);
  const float* ACb = AC + bg * QLEN * QLEN;
  const float* BDb = BD + bg * QLEN * QLEN;

  // phase A: T = (AC + BDshift) * SCALE
#pragma unroll 4
  for (int c = 0; c < 64; ++c) {
    const int idx = c * 256 + tid;
    const int rr = idx >> 10, j = idx & 1023;
    const int i = i0 + rr;
    float bd;
    if (j <= i)          bd = BDb[(size_t)i * QLEN + (j + QLEN - 1 - i)];
    else if (j == i + 1) bd = 0.f;
    else                 bd = BDb[(size_t)(i + 1) * QLEN + (j - i - 2)];
    T[rr * 1024 + j] = (__bf16)((ACb[(size_t)i * QLEN + j] + bd) * SCALE);
  }
  __syncthreads();

  const int lane = tid & 63, wv = tid >> 6;
  const int r  = wv * 4 + (lane >> 4);   // score-pass row 0..15
  const int li = lane & 15;              // score-pass lane-in-row
  const int m  = lane & 15;              // MFMA row/col
  const int kq = lane >> 4;

  const __bf16* mrow0 = masksP +           (size_t)(i0 + r) * 1024;
  const __bf16* mrow1 = masksP + 1048576 + (size_t)(i0 + r) * 1024;
  const __bf16* mrow2 = masksP + 2097152 + (size_t)(i0 + r) * 1024;

  for (int hh = 0; hh < 8; ++hh) {
    const int head = g * 8 + hh;
    const float mp0 = mproj[head], mp1 = mproj[16 + head], mp2 = mproj[32 + head];

    // pass 1: s = T * maskmix, rowmax, store bf16 (swizzled)
    float mx = -3.4e38f;
#pragma unroll
    for (int q = 0; q < 16; ++q) {
      const int jb = q * 64 + li * 4;
      const int jsw = (((jb >> 3) ^ (r & 7)) << 3) | (jb & 7);
      const bf16x4 t4 = *(const bf16x4*)&T[r * 1024 + jb];
      const bf16x4 m0 = *(const bf16x4*)&mrow0[jb];
      const bf16x4 m1 = *(const bf16x4*)&mrow1[jb];
      const bf16x4 m2 = *(const bf16x4*)&mrow2[jb];
      bf16x4 p4;
#pragma unroll
      for (int k = 0; k < 4; ++k) {
        const float mw = (float)m0[k] * mp0 + (float)m1[k] * mp1 + (float)m2[k] * mp2;
        const float s = (float)t4[k] * mw;
        mx = fmaxf(mx, s);
        p4[k] = (__bf16)s;
      }
      *(bf16x4*)&P[r * 1024 + jsw] = p4;
    }
    mx = fmaxf(mx, __shfl_xor(mx, 1));
    mx = fmaxf(mx, __shfl_xor(mx, 2));
    mx = fmaxf(mx, __shfl_xor(mx, 4));
    mx = fmaxf(mx, __shfl_xor(mx, 8));

    // pass 2: exp + rowsum
    float sum = 0.f;
#pragma unroll
    for (int q = 0; q < 16; ++q) {
      const int jb = q * 64 + li * 4;
      const int jsw = (((jb >> 3) ^ (r & 7)) << 3) | (jb & 7);
      bf16x4 p4 = *(bf16x4*)&P[r * 1024 + jsw];
#pragma unroll
      for (int k = 0; k < 4; ++k) {
        const float e = __expf((float)p4[k] - mx);
        sum += e;
        p4[k] = (__bf16)e;
      }
      *(bf16x4*)&P[r * 1024 + jsw] = p4;
    }
    sum += __shfl_xor(sum, 1);
    sum += __shfl_xor(sum, 2);
    sum += __shfl_xor(sum, 4);
    sum += __shfl_xor(sum, 8);
    const float rinv = 1.f / sum;

    // pass 3: pre-scale P by 1/rowsum (folds softmax denom into P)
#pragma unroll
    for (int q = 0; q < 16; ++q) {
      const int jb = q * 64 + li * 4;
      const int jsw = (((jb >> 3) ^ (r & 7)) << 3) | (jb & 7);
      bf16x4 p4 = *(bf16x4*)&P[r * 1024 + jsw];
#pragma unroll
      for (int k = 0; k < 4; ++k) p4[k] = (__bf16)((float)p4[k] * rinv);
      *(bf16x4*)&P[r * 1024 + jsw] = p4;
    }
    __syncthreads();

    // PV: wave wv covers d in [wv*16, wv*16+16); K = 1024 in 32 steps
    const __bf16* vbase = Vt + ((size_t)(b * 16 + head) * 64 + wv * 16 + m) * 1024 + kq * 8;
    f32x4 acc = (f32x4){0.f, 0.f, 0.f, 0.f};
#pragma unroll 8
    for (int ks = 0; ks < 32; ++ks) {
      const int c = ks * 4 + kq;  // 16B chunk index along j
      const bf16x8 a = *(const bf16x8*)&P[m * 1024 + ((c ^ (m & 7)) << 3)];
      const bf16x8 vv = *(const bf16x8*)&vbase[ks * 32];
      acc = __builtin_amdgcn_mfma_f32_16x16x32_bf16(a, vv, acc, 0, 0, 0);
    }
    // C/D: col = lane&15 (d-local), row = kq*4+reg (i-local)
#pragma unroll
    for (int reg = 0; reg < 4; ++reg) {
      const int row = kq * 4 + reg;
      av[((size_t)(i0 + row) * 4 + b) * 1024 + head * 64 + wv * 16 + m] = (__bf16)acc[reg];
    }
    __syncthreads();  // protect P before next head overwrites
  }
}

// ---------------------------------------------------------------------------
// residual + LayerNorm (unchanged)
// ---------------------------------------------------------------------------
__global__ __launch_bounds__(256) void ln_kernel(
    const float* __restrict__ w, const float* __restrict__ ao,
    const float* __restrict__ gamma, const float* __restrict__ beta,
    float* __restrict__ out)
{
  const int tid = threadIdx.x;
  const size_t base = (size_t)blockIdx.x * DMODEL;
  __shared__ float red[256];
  float x[4];
  float s = 0.f;
#pragma unroll
  for (int p = 0; p < 4; ++p) {
    const int c = tid + p * 256;
    x[p] = w[base + c] + ao[base + c];
    s += x[p];
  }
  red[tid] = s; __syncthreads();
  for (int off = 128; off > 0; off >>= 1) {
    if (tid < off) red[tid] += red[tid + off];
    __syncthreads();
  }
  const float mu = red[0] * (1.f / DMODEL);
  __syncthreads();
  float s2 = 0.f;
#pragma unroll
  for (int p = 0; p < 4; ++p) { const float t = x[p] - mu; s2 += t * t; }
  red[tid] = s2; __syncthreads();
  for (int off = 128; off > 0; off >>= 1) {
    if (tid < off) red[tid] += red[tid + off];
    __syncthreads();
  }
  const float rs = rsqrtf(red[0] * (1.f / DMODEL) + LN_EPS);
#pragma unroll
  for (int p = 0; p < 4; ++p) {
    const int c = tid + p * 256;
    out[base + c] = (x[p] - mu) * rs * gamma[c] + beta[c];
  }
}

// ---------------------------------------------------------------------------
extern "C" void kernel_launch(void* const* d_in, const int* in_sizes, int n_in,
                              void* d_out, int out_size, void* d_ws, size_t ws_size,
                              hipStream_t stream)
{
  const float* w     = (const float*)d_in[0];
  const float* r     = (const float*)d_in[1];
  const float* rwb   = (const float*)d_in[2];
  const float* rrb   = (const float*)d_in[3];
  const float* masks = (const float*)d_in[4];
  const float* Wqkv  = (const float*)d_in[5];
  const float* Wr    = (const float*)d_in[6];
  const float* mproj = (const float*)d_in[7];
  const float* Wo    = (const float*)d_in[8];
  const float* gam   = (const float*)d_in[9];
  const float* bet   = (const float*)d_in[10];
  float* out = (float*)d_out;

  float* ws = (float*)d_ws;
  float* wh = ws;                 // w_heads  [4096][1280] fp32 (dead after acbd)
  float* rk = wh + 5242880;       // r_head_k [1024][128]
  float* AC = rk + 131072;        // [8][1024][1024]
  float* BD = AC + 8388608;       // [8][1024][1024]
  float* av = BD + 8388608;       // [4096][1024] region (fp32-sized)
  float* ao = AC;                 // attn_out reuses AC (dead after attn2)

  __bf16* w_bf    = (__bf16*)BD;              // overlays BD (pre-acbd)
  __bf16* Wqkv_bf = (__bf16*)(BD + 2097152);
  __bf16* Wo_bf   = (__bf16*)BD;              // overlays BD (post-attn)
  __bf16* av_bf   = (__bf16*)av;              // first half of av region
  __bf16* Vt_bf   = (__bf16*)(av + 2097152);  // second half: [64*64][1024] bf16
  __bf16* masksP  = (__bf16*)wh;              // overlays wh (post-acbd)

  // 1) bf16 casts for QKV GEMM
  cast_bf16<<<2048, 256, 0, stream>>>(w, w_bf);
  cast_bf16<<<640, 256, 0, stream>>>(Wqkv, Wqkv_bf);
  // 2) QKV projection (bf16 MFMA)
  gemm_bf16<<<dim3(10, 32), 256, 0, stream>>>(w_bf, Wqkv_bf, wh, 1024, 1024, 1024, 1280);
  // 3) V transpose+cast (reads wh V-section)
  vt_cast<<<dim3(16, 64), 256, 0, stream>>>(wh, Vt_bf);
  // 4) r projection (small, fp32)
  gemm_abt<32, 32, 16, 2, 2><<<dim3(4, 32), 256, 0, stream>>>(
      r, Wr, rk, 1024, 128, 1024, 1024, 1024, 128);
  // 5) AC / BD batched GEMMs (reads wh Q,K; clobbers w_bf/Wqkv_bf overlay)
  acbd_kernel<<<dim3(16, 16, 8), 256, 0, stream>>>(wh, rk, rwb, rrb, AC, BD);
  // 6) planarize masks to bf16 (overlays wh -- wh fully dead now)
  cast_masks<<<1024, 256, 0, stream>>>(masks, masksP);
  // 7) fused rel-shift + mask mix + softmax + PV (MFMA)
  attn2<<<dim3(64, 2, 4), 256, 0, stream>>>(AC, BD, masksP, mproj, Vt_bf, av_bf);
  // 8) cast Wo (BD dead), output projection (bf16 MFMA) into ao (= AC region)
  cast_bf16<<<512, 256, 0, stream>>>(Wo, Wo_bf);
  gemm_bf16<<<dim3(8, 32), 256, 0, stream>>>(av_bf, Wo_bf, ao, 1024, 1024, 1024, 1024);
  // 9) residual + LayerNorm
  ln_kernel<<<4096, 256, 0, stream>>>(w, ao, gam, bet, out);
}

// Round 4
// 320.252 us; speedup vs baseline: 2.5841x; 1.4864x over previous
//
#include <hip/hip_runtime.h>
#include <cstddef>
#include <cstdint>

#define QLEN   1024
#define SCALE  0.125f
#define LN_EPS 1e-5f
#define DMODEL 1024

typedef __bf16 bf16x8 __attribute__((ext_vector_type(8)));
typedef __bf16 bf16x4 __attribute__((ext_vector_type(4)));
typedef float  f32x4  __attribute__((ext_vector_type(4)));

__device__ __forceinline__ void load16_lds(const void* g, void* l) {
  __builtin_amdgcn_global_load_lds(
      (const __attribute__((address_space(1))) unsigned int*)g,
      (__attribute__((address_space(3))) unsigned int*)l, 16, 0, 0);
}

// ---------------------------------------------------------------------------
// fp32 -> bf16 cast, 8 elements/thread.
// ---------------------------------------------------------------------------
__global__ __launch_bounds__(256) void cast_bf16(
    const float* __restrict__ in, __bf16* __restrict__ out)
{
  const size_t i = ((size_t)blockIdx.x * 256 + threadIdx.x) * 8;
  const float4 a = *(const float4*)&in[i];
  const float4 b = *(const float4*)&in[i + 4];
  bf16x8 o;
  o[0] = (__bf16)a.x; o[1] = (__bf16)a.y; o[2] = (__bf16)a.z; o[3] = (__bf16)a.w;
  o[4] = (__bf16)b.x; o[5] = (__bf16)b.y; o[6] = (__bf16)b.z; o[7] = (__bf16)b.w;
  *(bf16x8*)&out[i] = o;
}

// ---------------------------------------------------------------------------
// masks [1024*1024][3] fp32 -> 3 planar bf16 planes of 1048576.
// ---------------------------------------------------------------------------
__global__ __launch_bounds__(256) void cast_masks(
    const float* __restrict__ masks, __bf16* __restrict__ mp)
{
  const size_t ij0 = ((size_t)blockIdx.x * 256 + threadIdx.x) * 4;
  const float4 a = *(const float4*)&masks[ij0 * 3];
  const float4 b = *(const float4*)&masks[ij0 * 3 + 4];
  const float4 c = *(const float4*)&masks[ij0 * 3 + 8];
  bf16x4 p0, p1, p2;
  p0[0] = (__bf16)a.x; p0[1] = (__bf16)a.w; p0[2] = (__bf16)b.z; p0[3] = (__bf16)c.y;
  p1[0] = (__bf16)a.y; p1[1] = (__bf16)b.x; p1[2] = (__bf16)b.w; p1[3] = (__bf16)c.z;
  p2[0] = (__bf16)a.z; p2[1] = (__bf16)b.y; p2[2] = (__bf16)c.x; p2[3] = (__bf16)c.w;
  *(bf16x4*)&mp[ij0]           = p0;
  *(bf16x4*)&mp[1048576 + ij0] = p1;
  *(bf16x4*)&mp[2097152 + ij0] = p2;
}

// ---------------------------------------------------------------------------
// V transpose+cast from bf16 wh: wh[(j*4+b)*1280 + 256 + h*64 + d] ->
// Vt[((b*16+h)*64 + d)*1024 + j].  grid (16 jt, 64 bh).
// ---------------------------------------------------------------------------
__global__ __launch_bounds__(256) void vt_cast(
    const __bf16* __restrict__ wh, __bf16* __restrict__ Vt)
{
  __shared__ __bf16 tile[64][65];
  const int tid = threadIdx.x;
  const int jt = blockIdx.x, bh = blockIdx.y;
  const int b = bh >> 4, h = bh & 15;
#pragma unroll
  for (int p = 0; p < 16; ++p) {
    const int idx = p * 256 + tid;
    const int jj = idx >> 6, dd = idx & 63;
    tile[jj][dd] = wh[(size_t)((jt * 64 + jj) * 4 + b) * 1280 + 256 + h * 64 + dd];
  }
  __syncthreads();
#pragma unroll
  for (int p = 0; p < 16; ++p) {
    const int idx = p * 256 + tid;
    const int dd = idx >> 6, jj = idx & 63;
    Vt[((size_t)(bh * 64 + dd)) * 1024 + jt * 64 + jj] = tile[jj][dd];
  }
}

// ---------------------------------------------------------------------------
// Q/K/R prep: fold biases, repack to contiguous [bg][row][64] bf16.
// grid (64 rt, 8 bg), 256 thr.
// ---------------------------------------------------------------------------
__global__ __launch_bounds__(256) void qkr_prep(
    const __bf16* __restrict__ wh, const __bf16* __restrict__ rkb,
    const float* __restrict__ rwb, const float* __restrict__ rrb,
    __bf16* __restrict__ Qw, __bf16* __restrict__ Qr,
    __bf16* __restrict__ Kb, __bf16* __restrict__ Rb)
{
  const int bgi = blockIdx.y;
  const int b = bgi >> 1, g = bgi & 1;
  const int tid = threadIdx.x;
  const int r = blockIdx.x * 16 + (tid >> 4), li = tid & 15, d = li * 4;
  const size_t base = (size_t)bgi * 65536 + (size_t)r * 64 + d;
  const bf16x4 q4 = *(const bf16x4*)&wh[(size_t)(r * 4 + b) * 1280 + g * 64 + d];
  const bf16x4 k4 = *(const bf16x4*)&wh[(size_t)(r * 4 + b) * 1280 + 128 + g * 64 + d];
  const bf16x4 r4 = *(const bf16x4*)&rkb[(size_t)r * 128 + g * 64 + d];
  const float4 bw = *(const float4*)&rwb[g * 64 + d];
  const float4 br = *(const float4*)&rrb[g * 64 + d];
  bf16x4 qw, qr;
  qw[0] = (__bf16)((float)q4[0] + bw.x); qw[1] = (__bf16)((float)q4[1] + bw.y);
  qw[2] = (__bf16)((float)q4[2] + bw.z); qw[3] = (__bf16)((float)q4[3] + bw.w);
  qr[0] = (__bf16)((float)q4[0] + br.x); qr[1] = (__bf16)((float)q4[1] + br.y);
  qr[2] = (__bf16)((float)q4[2] + br.z); qr[3] = (__bf16)((float)q4[3] + br.w);
  *(bf16x4*)&Qw[base] = qw;
  *(bf16x4*)&Qr[base] = qr;
  *(bf16x4*)&Kb[base] = k4;
  *(bf16x4*)&Rb[base] = r4;
}

// ---------------------------------------------------------------------------
// bf16 MFMA GEMM (m97 recipe): C[m,n] = sum_k A[m,k]*B[n,k], OutT out.
// ---------------------------------------------------------------------------
template<typename OutT>
__global__ __launch_bounds__(256) void gemm_bf16(
    const __bf16* __restrict__ A, const __bf16* __restrict__ B,
    OutT* __restrict__ C, int K, int lda, int ldb, int ldc)
{
  __shared__ __bf16 Asl[128 * 32];
  __shared__ __bf16 Bsl[128 * 32];
  const int tid  = threadIdx.x;
  const int lane = tid & 63;
  const int wv   = tid >> 6;
  const int m0 = blockIdx.y * 128;
  const int n0 = blockIdx.x * 128;
  const int wm = (wv >> 1) * 64;
  const int wn = (wv & 1) * 64;
  const int lr = lane & 15;
  const int kq = lane >> 4;

  const int srow  = wv * 16 + (lane >> 2);
  const int sslot = lane & 3;
  const int sg0 = (sslot - ((srow >> 1) & 3)) & 3;
  const int sg1 = (sslot - (((srow + 64) >> 1) & 3)) & 3;
  const __bf16* Ag = A + (size_t)(m0 + srow) * lda;
  const __bf16* Bg = B + (size_t)(n0 + srow) * ldb;
  __bf16* Al = &Asl[srow * 32 + sslot * 8];
  __bf16* Bl = &Bsl[srow * 32 + sslot * 8];

  f32x4 acc[4][4];
#pragma unroll
  for (int mt = 0; mt < 4; ++mt)
#pragma unroll
    for (int nt = 0; nt < 4; ++nt)
      acc[mt][nt] = (f32x4){0.f, 0.f, 0.f, 0.f};

  for (int k0 = 0; k0 < K; k0 += 32) {
    load16_lds(Ag + k0 + sg0 * 8, Al);
    load16_lds(Ag + (size_t)64 * lda + k0 + sg1 * 8, Al + 64 * 32);
    load16_lds(Bg + k0 + sg0 * 8, Bl);
    load16_lds(Bg + (size_t)64 * ldb + k0 + sg1 * 8, Bl + 64 * 32);
    __syncthreads();

    bf16x8 af[4], bfr[4];
#pragma unroll
    for (int mt = 0; mt < 4; ++mt) {
      const int row = wm + mt * 16 + lr;
      af[mt] = *(const bf16x8*)&Asl[row * 32 + ((kq + (row >> 1)) & 3) * 8];
    }
#pragma unroll
    for (int nt = 0; nt < 4; ++nt) {
      const int row = wn + nt * 16 + lr;
      bfr[nt] = *(const bf16x8*)&Bsl[row * 32 + ((kq + (row >> 1)) & 3) * 8];
    }
#pragma unroll
    for (int mt = 0; mt < 4; ++mt)
#pragma unroll
      for (int nt = 0; nt < 4; ++nt)
        acc[mt][nt] = __builtin_amdgcn_mfma_f32_16x16x32_bf16(
            af[mt], bfr[nt], acc[mt][nt], 0, 0, 0);
    __syncthreads();
  }

#pragma unroll
  for (int mt = 0; mt < 4; ++mt) {
    const int row0 = m0 + wm + mt * 16 + kq * 4;
#pragma unroll
    for (int nt = 0; nt < 4; ++nt) {
      const int col = n0 + wn + nt * 16 + lr;
      const f32x4 c = acc[mt][nt];
#pragma unroll
      for (int reg = 0; reg < 4; ++reg)
        C[(size_t)(row0 + reg) * ldc + col] = (OutT)c[reg];
    }
  }
}

// ---------------------------------------------------------------------------
// Batched K=64 bf16 MFMA GEMM for AC/BD:
// z = bat*2 + which: which=0 -> AC = Qw·Kb^T, which=1 -> BD = Qr·Rb^T.
// 128x128 tile, whole K=64 staged once (32 KB LDS), output bf16.
// grid (8 jt, 8 it, 16).
// ---------------------------------------------------------------------------
__global__ __launch_bounds__(256) void gemm64_bf16(
    const __bf16* __restrict__ Qw, const __bf16* __restrict__ Qr,
    const __bf16* __restrict__ Kb, const __bf16* __restrict__ Rb,
    __bf16* __restrict__ AC, __bf16* __restrict__ BDo)
{
  __shared__ __bf16 Asl[128 * 64];
  __shared__ __bf16 Bsl[128 * 64];
  const int tid = threadIdx.x, lane = tid & 63, wv = tid >> 6;
  const int which = blockIdx.z & 1, bat = blockIdx.z >> 1;
  const int m0 = blockIdx.y * 128, n0 = blockIdx.x * 128;
  const __bf16* Ap = (which ? Qr : Qw) + (size_t)bat * 65536;
  const __bf16* Bp = (which ? Rb : Kb) + (size_t)bat * 65536;
  __bf16* Cp = (which ? BDo : AC) + (size_t)bat * 1048576;

  // stage: row stride 64 bf16 = 8 chunks of 16B; chunk rotation by row&7 on
  // the GLOBAL side so LDS dest stays waveBase + lane*16.
#pragma unroll
  for (int p = 0; p < 4; ++p) {
    const int row = wv * 32 + p * 8 + (lane >> 3);
    const int s = lane & 7;
    const int gc = (s - (row & 7)) & 7;
    load16_lds(Ap + (size_t)(m0 + row) * 64 + gc * 8, &Asl[row * 64 + s * 8]);
    load16_lds(Bp + (size_t)(n0 + row) * 64 + gc * 8, &Bsl[row * 64 + s * 8]);
  }
  __syncthreads();

  const int lr = lane & 15, kq = lane >> 4;
  const int wm = (wv >> 1) * 64, wn = (wv & 1) * 64;
  f32x4 acc[4][4];
#pragma unroll
  for (int mt = 0; mt < 4; ++mt)
#pragma unroll
    for (int nt = 0; nt < 4; ++nt)
      acc[mt][nt] = (f32x4){0.f, 0.f, 0.f, 0.f};

#pragma unroll
  for (int ks = 0; ks < 2; ++ks) {
    const int c = ks * 4 + kq;
    bf16x8 af[4], bfr[4];
#pragma unroll
    for (int mt = 0; mt < 4; ++mt) {
      const int row = wm + mt * 16 + lr;
      af[mt] = *(const bf16x8*)&Asl[row * 64 + ((c + (row & 7)) & 7) * 8];
    }
#pragma unroll
    for (int nt = 0; nt < 4; ++nt) {
      const int row = wn + nt * 16 + lr;
      bfr[nt] = *(const bf16x8*)&Bsl[row * 64 + ((c + (row & 7)) & 7) * 8];
    }
#pragma unroll
    for (int mt = 0; mt < 4; ++mt)
#pragma unroll
      for (int nt = 0; nt < 4; ++nt)
        acc[mt][nt] = __builtin_amdgcn_mfma_f32_16x16x32_bf16(
            af[mt], bfr[nt], acc[mt][nt], 0, 0, 0);
  }

#pragma unroll
  for (int mt = 0; mt < 4; ++mt) {
    const int row0 = m0 + wm + mt * 16 + kq * 4;
#pragma unroll
    for (int nt = 0; nt < 4; ++nt) {
      const int col = n0 + wn + nt * 16 + lr;
      const f32x4 cc = acc[mt][nt];
#pragma unroll
      for (int reg = 0; reg < 4; ++reg)
        Cp[(size_t)(row0 + reg) * 1024 + col] = (__bf16)cc[reg];
    }
  }
}

// ---------------------------------------------------------------------------
// tshift: T[bg][i][j] = (AC[bg][i][j] + BDshift[bg][i][j]) * SCALE, bf16.
// BDshift row i = [BD[i, N-1-i .. N-1], 0, BD[i+1, 0 .. N-i-3]].
// grid 2048 (= 8 bg * 256 row-quads), 256 thr = 4 rows x 64 lanes.
// ---------------------------------------------------------------------------
__global__ __launch_bounds__(256) void tshift(
    const __bf16* __restrict__ AC, const __bf16* __restrict__ BDm,
    __bf16* __restrict__ Tg)
{
  const int blk = blockIdx.x;
  const size_t bg = blk >> 8;
  const int tid = threadIdx.x;
  const int i = (blk & 255) * 4 + (tid >> 6);
  const int lane = tid & 63;
  const __bf16* ACr = AC + bg * 1048576 + (size_t)i * 1024;
  const __bf16* BDb = BDm + bg * 1048576;
  __bf16* Tr = Tg + bg * 1048576 + (size_t)i * 1024;
#pragma unroll
  for (int c2 = 0; c2 < 4; ++c2) {
    const int j0 = c2 * 256 + lane * 4;
    const bf16x4 ac4 = *(const bf16x4*)&ACr[j0];
    bf16x4 o;
#pragma unroll
    for (int k = 0; k < 4; ++k) {
      const int j = j0 + k;
      float bd;
      if (j <= i)          bd = (float)BDb[(size_t)i * 1024 + (j + QLEN - 1 - i)];
      else if (j == i + 1) bd = 0.f;
      else                 bd = (float)BDb[(size_t)(i + 1) * 1024 + (j - i - 2)];
      o[k] = (__bf16)(((float)ac4[k] + bd) * SCALE);
    }
    *(bf16x4*)&Tr[j0] = o;
  }
}

// ---------------------------------------------------------------------------
// attn3: one block = (16 rows, one head, one batch). Scores in REGISTERS,
// P written to LDS once; 1/rowsum folded post-MFMA. 1 barrier per block.
// grid (64, 16, 4), 256 thr, LDS 32 KB.
// ---------------------------------------------------------------------------
__global__ __launch_bounds__(256) void attn3(
    const __bf16* __restrict__ Tg, const __bf16* __restrict__ masksP,
    const float* __restrict__ mproj, const __bf16* __restrict__ Vt,
    __bf16* __restrict__ av)
{
  __shared__ __bf16 P[16 * 1024];
  __shared__ float rinvS[16];
  const int tid = threadIdx.x;
  const int i0 = blockIdx.x * 16;
  const int h = blockIdx.y, b = blockIdx.z;
  const int g = h >> 3;
  const size_t bg = (size_t)(b * 2 + g);
  const int r = tid >> 4, li = tid & 15;
  const float mp0 = mproj[h], mp1 = mproj[16 + h], mp2 = mproj[32 + h];
  const __bf16* Trow = Tg + bg * 1048576 + (size_t)(i0 + r) * 1024;
  const __bf16* m0r = masksP + (size_t)(i0 + r) * 1024;
  const __bf16* m1r = m0r + 1048576;
  const __bf16* m2r = m0r + 2097152;

  // pass 1: scores into registers (bf16x4 x16 = 32 VGPRs), rowmax
  bf16x4 sreg[16];
  float mx = -3.4e38f;
#pragma unroll
  for (int q = 0; q < 16; ++q) {
    const int jb = q * 64 + li * 4;
    const bf16x4 t4 = *(const bf16x4*)&Trow[jb];
    const bf16x4 a0 = *(const bf16x4*)&m0r[jb];
    const bf16x4 a1 = *(const bf16x4*)&m1r[jb];
    const bf16x4 a2 = *(const bf16x4*)&m2r[jb];
    bf16x4 s4;
#pragma unroll
    for (int k = 0; k < 4; ++k) {
      const float mw = (float)a0[k] * mp0 + (float)a1[k] * mp1 + (float)a2[k] * mp2;
      const float s = (float)t4[k] * mw;
      mx = fmaxf(mx, s);
      s4[k] = (__bf16)s;
    }
    sreg[q] = s4;
  }
  mx = fmaxf(mx, __shfl_xor(mx, 1));
  mx = fmaxf(mx, __shfl_xor(mx, 2));
  mx = fmaxf(mx, __shfl_xor(mx, 4));
  mx = fmaxf(mx, __shfl_xor(mx, 8));

  // pass 2: exp from regs, write P (swizzled) once, rowsum
  float sum = 0.f;
#pragma unroll
  for (int q = 0; q < 16; ++q) {
    const int jb = q * 64 + li * 4;
    const int jsw = (((jb >> 3) ^ (r & 7)) << 3) | (jb & 7);
    bf16x4 p4;
#pragma unroll
    for (int k = 0; k < 4; ++k) {
      const float e = __expf((float)sreg[q][k] - mx);
      sum += e;
      p4[k] = (__bf16)e;
    }
    *(bf16x4*)&P[r * 1024 + jsw] = p4;
  }
  sum += __shfl_xor(sum, 1);
  sum += __shfl_xor(sum, 2);
  sum += __shfl_xor(sum, 4);
  sum += __shfl_xor(sum, 8);
  if (li == 0) rinvS[r] = 1.f / sum;
  __syncthreads();

  // PV: wave wv covers d in [wv*16, wv*16+16)
  const int lane = tid & 63, wv = tid >> 6;
  const int m = lane & 15, kq = lane >> 4;
  const __bf16* vbase = Vt + ((size_t)(b * 16 + h) * 64 + wv * 16 + m) * 1024 + kq * 8;
  f32x4 acc = (f32x4){0.f, 0.f, 0.f, 0.f};
#pragma unroll 8
  for (int ks = 0; ks < 32; ++ks) {
    const int c = ks * 4 + kq;
    const bf16x8 a = *(const bf16x8*)&P[m * 1024 + ((c ^ (m & 7)) << 3)];
    const bf16x8 vv = *(const bf16x8*)&vbase[ks * 32];
    acc = __builtin_amdgcn_mfma_f32_16x16x32_bf16(a, vv, acc, 0, 0, 0);
  }
#pragma unroll
  for (int reg = 0; reg < 4; ++reg) {
    const int row = kq * 4 + reg;
    av[((size_t)(i0 + row) * 4 + b) * 1024 + h * 64 + wv * 16 + m] =
        (__bf16)(acc[reg] * rinvS[row]);
  }
}

// ---------------------------------------------------------------------------
// residual + LayerNorm
// ---------------------------------------------------------------------------
__global__ __launch_bounds__(256) void ln_kernel(
    const float* __restrict__ w, const float* __restrict__ ao,
    const float* __restrict__ gamma, const float* __restrict__ beta,
    float* __restrict__ out)
{
  const int tid = threadIdx.x;
  const size_t base = (size_t)blockIdx.x * DMODEL;
  __shared__ float red[256];
  float x[4];
  float s = 0.f;
#pragma unroll
  for (int p = 0; p < 4; ++p) {
    const int c = tid + p * 256;
    x[p] = w[base + c] + ao[base + c];
    s += x[p];
  }
  red[tid] = s; __syncthreads();
  for (int off = 128; off > 0; off >>= 1) {
    if (tid < off) red[tid] += red[tid + off];
    __syncthreads();
  }
  const float mu = red[0] * (1.f / DMODEL);
  __syncthreads();
  float s2 = 0.f;
#pragma unroll
  for (int p = 0; p < 4; ++p) { const float t = x[p] - mu; s2 += t * t; }
  red[tid] = s2; __syncthreads();
  for (int off = 128; off > 0; off >>= 1) {
    if (tid < off) red[tid] += red[tid + off];
    __syncthreads();
  }
  const float rs = rsqrtf(red[0] * (1.f / DMODEL) + LN_EPS);
#pragma unroll
  for (int p = 0; p < 4; ++p) {
    const int c = tid + p * 256;
    out[base + c] = (x[p] - mu) * rs * gamma[c] + beta[c];
  }
}

// ---------------------------------------------------------------------------
extern "C" void kernel_launch(void* const* d_in, const int* in_sizes, int n_in,
                              void* d_out, int out_size, void* d_ws, size_t ws_size,
                              hipStream_t stream)
{
  const float* w     = (const float*)d_in[0];
  const float* r     = (const float*)d_in[1];
  const float* rwb   = (const float*)d_in[2];
  const float* rrb   = (const float*)d_in[3];
  const float* masks = (const float*)d_in[4];
  const float* Wqkv  = (const float*)d_in[5];
  const float* Wr    = (const float*)d_in[6];
  const float* mproj = (const float*)d_in[7];
  const float* Wo    = (const float*)d_in[8];
  const float* gam   = (const float*)d_in[9];
  const float* bet   = (const float*)d_in[10];
  float* out = (float*)d_out;

  float* ws = (float*)d_ws;
  // layout (fp32-unit offsets; total 26,279,936 f = 105.1 MB)
  __bf16* wh_bf   = (__bf16*)(ws);                   // [4096][1280]
  __bf16* rk_bf   = (__bf16*)(ws + 2621440);         // [1024][128]
  __bf16* Qw      = (__bf16*)(ws + 2686976);         // [8][1024][64]
  __bf16* Qr      = (__bf16*)(ws + 2949120);
  __bf16* Kb      = (__bf16*)(ws + 3211264);
  __bf16* Rb      = (__bf16*)(ws + 3473408);
  __bf16* AC_bf   = (__bf16*)(ws + 3735552);         // [8][1024][1024]
  __bf16* BD_bf   = (__bf16*)(ws + 7929856);         // [8][1024][1024]
  __bf16* Tg      = (__bf16*)(ws + 12124160);        // [8][1024][1024]
  __bf16* masksP  = (__bf16*)(ws + 16318464);        // 3 x [1024][1024]
  __bf16* Vt      = (__bf16*)(ws + 17891328);        // [64][64][1024]
  __bf16* av_bf   = (__bf16*)(ws + 19988480);        // [4096][1024]
  float*  ao      = ws + 22085632;                   // [4096][1024] fp32
  // overlays (dead-region reuse):
  __bf16* w_bf    = (__bf16*)(ws + 3735552);         // AC region, pre-acbd
  __bf16* Wqkv_bf = (__bf16*)(ws + 5832704);         // AC region, pre-acbd
  __bf16* r_bf    = (__bf16*)(ws + 7929856);         // BD region, pre-acbd
  __bf16* Wr_bf   = (__bf16*)(ws + 8454144);         // BD region, pre-acbd
  __bf16* Wo_bf   = (__bf16*)(ws + 3735552);         // AC region, post-tshift

  // 1) input casts
  cast_bf16<<<2048, 256, 0, stream>>>(w, w_bf);
  cast_bf16<<<640, 256, 0, stream>>>(Wqkv, Wqkv_bf);
  cast_bf16<<<512, 256, 0, stream>>>(r, r_bf);
  cast_bf16<<<64, 256, 0, stream>>>(Wr, Wr_bf);
  // 2) QKV projection -> bf16 wh
  gemm_bf16<__bf16><<<dim3(10, 32), 256, 0, stream>>>(
      w_bf, Wqkv_bf, wh_bf, 1024, 1024, 1024, 1280);
  // 3) r projection -> bf16 rk
  gemm_bf16<__bf16><<<dim3(1, 8), 256, 0, stream>>>(
      r_bf, Wr_bf, rk_bf, 1024, 1024, 1024, 128);
  // 4) V transpose, Q/K/R prep
  vt_cast<<<dim3(16, 64), 256, 0, stream>>>(wh_bf, Vt);
  qkr_prep<<<dim3(64, 8), 256, 0, stream>>>(wh_bf, rk_bf, rwb, rrb, Qw, Qr, Kb, Rb);
  // 5) AC/BD via MFMA (clobbers w_bf/Wqkv_bf/r_bf/Wr_bf overlays - dead)
  gemm64_bf16<<<dim3(8, 8, 16), 256, 0, stream>>>(Qw, Qr, Kb, Rb, AC_bf, BD_bf);
  // 6) masks planarize
  cast_masks<<<1024, 256, 0, stream>>>(masks, masksP);
  // 7) rel-shift fold: T = (AC + BDshift) * SCALE
  tshift<<<2048, 256, 0, stream>>>(AC_bf, BD_bf, Tg);
  // 8) Wo cast (AC region dead now)
  cast_bf16<<<512, 256, 0, stream>>>(Wo, Wo_bf);
  // 9) attention: mask-mix + softmax + PV
  attn3<<<dim3(64, 16, 4), 256, 0, stream>>>(Tg, masksP, mproj, Vt, av_bf);
  // 10) output projection -> fp32 ao
  gemm_bf16<float><<<dim3(8, 32), 256, 0, stream>>>(
      av_bf, Wo_bf, ao, 1024, 1024, 1024, 1024);
  // 11) residual + LayerNorm
  ln_kernel<<<4096, 256, 0, stream>>>(w, ao, gam, bet, out);
}

// Round 5
// 300.943 us; speedup vs baseline: 2.7499x; 1.0642x over previous
//
#include <hip/hip_runtime.h>
#include <cstddef>
#include <cstdint>

#define QLEN   1024
#define SCALE  0.125f
#define LN_EPS 1e-5f
#define DMODEL 1024

typedef __bf16 bf16x8 __attribute__((ext_vector_type(8)));
typedef __bf16 bf16x4 __attribute__((ext_vector_type(4)));
typedef float  f32x4  __attribute__((ext_vector_type(4)));

__device__ __forceinline__ void load16_lds(const void* g, void* l) {
  __builtin_amdgcn_global_load_lds(
      (const __attribute__((address_space(1))) unsigned int*)g,
      (__attribute__((address_space(3))) unsigned int*)l, 16, 0, 0);
}

// ---------------------------------------------------------------------------
// One cast kernel for all five fp32->bf16 inputs (block-range partitioned).
// 2048 elems per block.
// ---------------------------------------------------------------------------
__global__ __launch_bounds__(256) void cast_all(
    const float* __restrict__ w, __bf16* __restrict__ w_bf,
    const float* __restrict__ Wqkv, __bf16* __restrict__ Wqkv_bf,
    const float* __restrict__ r, __bf16* __restrict__ r_bf,
    const float* __restrict__ Wr, __bf16* __restrict__ Wr_bf,
    const float* __restrict__ Wo, __bf16* __restrict__ Wo_bf)
{
  int blk = blockIdx.x;
  const float* in; __bf16* out;
  if (blk < 2048)      { in = w;    out = w_bf;    }
  else if (blk < 2688) { blk -= 2048; in = Wqkv; out = Wqkv_bf; }
  else if (blk < 3200) { blk -= 2688; in = r;    out = r_bf;    }
  else if (blk < 3264) { blk -= 3200; in = Wr;   out = Wr_bf;   }
  else                 { blk -= 3264; in = Wo;   out = Wo_bf;   }
  const size_t i = ((size_t)blk * 256 + threadIdx.x) * 8;
  const float4 a = *(const float4*)&in[i];
  const float4 b = *(const float4*)&in[i + 4];
  bf16x8 o;
  o[0] = (__bf16)a.x; o[1] = (__bf16)a.y; o[2] = (__bf16)a.z; o[3] = (__bf16)a.w;
  o[4] = (__bf16)b.x; o[5] = (__bf16)b.y; o[6] = (__bf16)b.z; o[7] = (__bf16)b.w;
  *(bf16x8*)&out[i] = o;
}

// ---------------------------------------------------------------------------
// Per-head mixed masks: Mh[h][ij] = sum_l masks[ij][l]*mproj[l][h], bf16.
// grid 1024, 256 thr, 4 ij per thread (reads masks ONCE for all 16 heads).
// ---------------------------------------------------------------------------
__global__ __launch_bounds__(256) void mh_prep(
    const float* __restrict__ masks, const float* __restrict__ mproj,
    __bf16* __restrict__ Mh)
{
  const size_t ij0 = ((size_t)blockIdx.x * 256 + threadIdx.x) * 4;
  const float4 a = *(const float4*)&masks[ij0 * 3];
  const float4 b = *(const float4*)&masks[ij0 * 3 + 4];
  const float4 c = *(const float4*)&masks[ij0 * 3 + 8];
  const float m0[4] = {a.x, a.w, b.z, c.y};
  const float m1[4] = {a.y, b.x, b.w, c.z};
  const float m2[4] = {a.z, b.y, c.x, c.w};
#pragma unroll
  for (int h = 0; h < 16; ++h) {
    const float p0 = mproj[h], p1 = mproj[16 + h], p2 = mproj[32 + h];
    bf16x4 o;
#pragma unroll
    for (int k = 0; k < 4; ++k)
      o[k] = (__bf16)(m0[k] * p0 + m1[k] * p1 + m2[k] * p2);
    *(bf16x4*)&Mh[(size_t)h * 1048576 + ij0] = o;
  }
}

// ---------------------------------------------------------------------------
// V transpose from bf16 wh: wh[(j*4+b)*1280 + 256 + h*64 + d] ->
// Vt[((b*16+h)*64 + d)*1024 + j].  grid (16 jt, 64 bh).
// ---------------------------------------------------------------------------
__global__ __launch_bounds__(256) void vt_cast(
    const __bf16* __restrict__ wh, __bf16* __restrict__ Vt)
{
  __shared__ __bf16 tile[64][65];
  const int tid = threadIdx.x;
  const int jt = blockIdx.x, bh = blockIdx.y;
  const int b = bh >> 4, h = bh & 15;
#pragma unroll
  for (int p = 0; p < 16; ++p) {
    const int idx = p * 256 + tid;
    const int jj = idx >> 6, dd = idx & 63;
    tile[jj][dd] = wh[(size_t)((jt * 64 + jj) * 4 + b) * 1280 + 256 + h * 64 + dd];
  }
  __syncthreads();
#pragma unroll
  for (int p = 0; p < 16; ++p) {
    const int idx = p * 256 + tid;
    const int dd = idx >> 6, jj = idx & 63;
    Vt[((size_t)(bh * 64 + dd)) * 1024 + jt * 64 + jj] = tile[jj][dd];
  }
}

// ---------------------------------------------------------------------------
// Q/K/R prep: fold biases, repack to contiguous [bg][row][64] bf16.
// ---------------------------------------------------------------------------
__global__ __launch_bounds__(256) void qkr_prep(
    const __bf16* __restrict__ wh, const __bf16* __restrict__ rkb,
    const float* __restrict__ rwb, const float* __restrict__ rrb,
    __bf16* __restrict__ Qw, __bf16* __restrict__ Qr,
    __bf16* __restrict__ Kb, __bf16* __restrict__ Rb)
{
  const int bgi = blockIdx.y;
  const int b = bgi >> 1, g = bgi & 1;
  const int tid = threadIdx.x;
  const int r = blockIdx.x * 16 + (tid >> 4), li = tid & 15, d = li * 4;
  const size_t base = (size_t)bgi * 65536 + (size_t)r * 64 + d;
  const bf16x4 q4 = *(const bf16x4*)&wh[(size_t)(r * 4 + b) * 1280 + g * 64 + d];
  const bf16x4 k4 = *(const bf16x4*)&wh[(size_t)(r * 4 + b) * 1280 + 128 + g * 64 + d];
  const bf16x4 r4 = *(const bf16x4*)&rkb[(size_t)r * 128 + g * 64 + d];
  const float4 bw = *(const float4*)&rwb[g * 64 + d];
  const float4 br = *(const float4*)&rrb[g * 64 + d];
  bf16x4 qw, qr;
  qw[0] = (__bf16)((float)q4[0] + bw.x); qw[1] = (__bf16)((float)q4[1] + bw.y);
  qw[2] = (__bf16)((float)q4[2] + bw.z); qw[3] = (__bf16)((float)q4[3] + bw.w);
  qr[0] = (__bf16)((float)q4[0] + br.x); qr[1] = (__bf16)((float)q4[1] + br.y);
  qr[2] = (__bf16)((float)q4[2] + br.z); qr[3] = (__bf16)((float)q4[3] + br.w);
  *(bf16x4*)&Qw[base] = qw;
  *(bf16x4*)&Qr[base] = qr;
  *(bf16x4*)&Kb[base] = k4;
  *(bf16x4*)&Rb[base] = r4;
}

// ---------------------------------------------------------------------------
// bf16 MFMA GEMM (m97 recipe): C[m,n] = sum_k A[m,k]*B[n,k], OutT out.
// ---------------------------------------------------------------------------
template<typename OutT>
__global__ __launch_bounds__(256) void gemm_bf16(
    const __bf16* __restrict__ A, const __bf16* __restrict__ B,
    OutT* __restrict__ C, int K, int lda, int ldb, int ldc)
{
  __shared__ __bf16 Asl[128 * 32];
  __shared__ __bf16 Bsl[128 * 32];
  const int tid  = threadIdx.x;
  const int lane = tid & 63;
  const int wv   = tid >> 6;
  const int m0 = blockIdx.y * 128;
  const int n0 = blockIdx.x * 128;
  const int wm = (wv >> 1) * 64;
  const int wn = (wv & 1) * 64;
  const int lr = lane & 15;
  const int kq = lane >> 4;

  const int srow  = wv * 16 + (lane >> 2);
  const int sslot = lane & 3;
  const int sg0 = (sslot - ((srow >> 1) & 3)) & 3;
  const int sg1 = (sslot - (((srow + 64) >> 1) & 3)) & 3;
  const __bf16* Ag = A + (size_t)(m0 + srow) * lda;
  const __bf16* Bg = B + (size_t)(n0 + srow) * ldb;
  __bf16* Al = &Asl[srow * 32 + sslot * 8];
  __bf16* Bl = &Bsl[srow * 32 + sslot * 8];

  f32x4 acc[4][4];
#pragma unroll
  for (int mt = 0; mt < 4; ++mt)
#pragma unroll
    for (int nt = 0; nt < 4; ++nt)
      acc[mt][nt] = (f32x4){0.f, 0.f, 0.f, 0.f};

  for (int k0 = 0; k0 < K; k0 += 32) {
    load16_lds(Ag + k0 + sg0 * 8, Al);
    load16_lds(Ag + (size_t)64 * lda + k0 + sg1 * 8, Al + 64 * 32);
    load16_lds(Bg + k0 + sg0 * 8, Bl);
    load16_lds(Bg + (size_t)64 * ldb + k0 + sg1 * 8, Bl + 64 * 32);
    __syncthreads();

    bf16x8 af[4], bfr[4];
#pragma unroll
    for (int mt = 0; mt < 4; ++mt) {
      const int row = wm + mt * 16 + lr;
      af[mt] = *(const bf16x8*)&Asl[row * 32 + ((kq + (row >> 1)) & 3) * 8];
    }
#pragma unroll
    for (int nt = 0; nt < 4; ++nt) {
      const int row = wn + nt * 16 + lr;
      bfr[nt] = *(const bf16x8*)&Bsl[row * 32 + ((kq + (row >> 1)) & 3) * 8];
    }
#pragma unroll
    for (int mt = 0; mt < 4; ++mt)
#pragma unroll
      for (int nt = 0; nt < 4; ++nt)
        acc[mt][nt] = __builtin_amdgcn_mfma_f32_16x16x32_bf16(
            af[mt], bfr[nt], acc[mt][nt], 0, 0, 0);
    __syncthreads();
  }

#pragma unroll
  for (int mt = 0; mt < 4; ++mt) {
    const int row0 = m0 + wm + mt * 16 + kq * 4;
#pragma unroll
    for (int nt = 0; nt < 4; ++nt) {
      const int col = n0 + wn + nt * 16 + lr;
      const f32x4 c = acc[mt][nt];
#pragma unroll
      for (int reg = 0; reg < 4; ++reg)
        C[(size_t)(row0 + reg) * ldc + col] = (OutT)c[reg];
    }
  }
}

// ---------------------------------------------------------------------------
// Batched K=64 bf16 MFMA GEMM for AC/BD.
// ---------------------------------------------------------------------------
__global__ __launch_bounds__(256) void gemm64_bf16(
    const __bf16* __restrict__ Qw, const __bf16* __restrict__ Qr,
    const __bf16* __restrict__ Kb, const __bf16* __restrict__ Rb,
    __bf16* __restrict__ AC, __bf16* __restrict__ BDo)
{
  __shared__ __bf16 Asl[128 * 64];
  __shared__ __bf16 Bsl[128 * 64];
  const int tid = threadIdx.x, lane = tid & 63, wv = tid >> 6;
  const int which = blockIdx.z & 1, bat = blockIdx.z >> 1;
  const int m0 = blockIdx.y * 128, n0 = blockIdx.x * 128;
  const __bf16* Ap = (which ? Qr : Qw) + (size_t)bat * 65536;
  const __bf16* Bp = (which ? Rb : Kb) + (size_t)bat * 65536;
  __bf16* Cp = (which ? BDo : AC) + (size_t)bat * 1048576;

#pragma unroll
  for (int p = 0; p < 4; ++p) {
    const int row = wv * 32 + p * 8 + (lane >> 3);
    const int s = lane & 7;
    const int gc = (s - (row & 7)) & 7;
    load16_lds(Ap + (size_t)(m0 + row) * 64 + gc * 8, &Asl[row * 64 + s * 8]);
    load16_lds(Bp + (size_t)(n0 + row) * 64 + gc * 8, &Bsl[row * 64 + s * 8]);
  }
  __syncthreads();

  const int lr = lane & 15, kq = lane >> 4;
  const int wm = (wv >> 1) * 64, wn = (wv & 1) * 64;
  f32x4 acc[4][4];
#pragma unroll
  for (int mt = 0; mt < 4; ++mt)
#pragma unroll
    for (int nt = 0; nt < 4; ++nt)
      acc[mt][nt] = (f32x4){0.f, 0.f, 0.f, 0.f};

#pragma unroll
  for (int ks = 0; ks < 2; ++ks) {
    const int c = ks * 4 + kq;
    bf16x8 af[4], bfr[4];
#pragma unroll
    for (int mt = 0; mt < 4; ++mt) {
      const int row = wm + mt * 16 + lr;
      af[mt] = *(const bf16x8*)&Asl[row * 64 + ((c + (row & 7)) & 7) * 8];
    }
#pragma unroll
    for (int nt = 0; nt < 4; ++nt) {
      const int row = wn + nt * 16 + lr;
      bfr[nt] = *(const bf16x8*)&Bsl[row * 64 + ((c + (row & 7)) & 7) * 8];
    }
#pragma unroll
    for (int mt = 0; mt < 4; ++mt)
#pragma unroll
      for (int nt = 0; nt < 4; ++nt)
        acc[mt][nt] = __builtin_amdgcn_mfma_f32_16x16x32_bf16(
            af[mt], bfr[nt], acc[mt][nt], 0, 0, 0);
  }

#pragma unroll
  for (int mt = 0; mt < 4; ++mt) {
    const int row0 = m0 + wm + mt * 16 + kq * 4;
#pragma unroll
    for (int nt = 0; nt < 4; ++nt) {
      const int col = n0 + wn + nt * 16 + lr;
      const f32x4 cc = acc[mt][nt];
#pragma unroll
      for (int reg = 0; reg < 4; ++reg)
        Cp[(size_t)(row0 + reg) * 1024 + col] = (__bf16)cc[reg];
    }
  }
}

// ---------------------------------------------------------------------------
// tshift: T[bg][i][j] = (AC[bg][i][j] + BDshift[bg][i][j]) * SCALE, bf16.
// ---------------------------------------------------------------------------
__global__ __launch_bounds__(256) void tshift(
    const __bf16* __restrict__ AC, const __bf16* __restrict__ BDm,
    __bf16* __restrict__ Tg)
{
  const int blk = blockIdx.x;
  const size_t bg = blk >> 8;
  const int tid = threadIdx.x;
  const int i = (blk & 255) * 4 + (tid >> 6);
  const int lane = tid & 63;
  const __bf16* ACr = AC + bg * 1048576 + (size_t)i * 1024;
  const __bf16* BDb = BDm + bg * 1048576;
  __bf16* Tr = Tg + bg * 1048576 + (size_t)i * 1024;
#pragma unroll
  for (int c2 = 0; c2 < 4; ++c2) {
    const int j0 = c2 * 256 + lane * 4;
    const bf16x4 ac4 = *(const bf16x4*)&ACr[j0];
    bf16x4 o;
#pragma unroll
    for (int k = 0; k < 4; ++k) {
      const int j = j0 + k;
      float bd;
      if (j <= i)          bd = (float)BDb[(size_t)i * 1024 + (j + QLEN - 1 - i)];
      else if (j == i + 1) bd = 0.f;
      else                 bd = (float)BDb[(size_t)(i + 1) * 1024 + (j - i - 2)];
      o[k] = (__bf16)(((float)ac4[k] + bd) * SCALE);
    }
    *(bf16x4*)&Tr[j0] = o;
  }
}

// ---------------------------------------------------------------------------
// attn4: single-pass scores (no max subtraction -- |s| <= ~8 analytically,
// fp32 exp is safe), bf16x8 loads, P to LDS once, 1/rowsum post-MFMA.
// grid (64, 16, 4), 256 thr, LDS 32KB + 64B.
// ---------------------------------------------------------------------------
__global__ __launch_bounds__(256) void attn4(
    const __bf16* __restrict__ Tg, const __bf16* __restrict__ Mh,
    const __bf16* __restrict__ Vt, __bf16* __restrict__ av)
{
  __shared__ __bf16 P[16 * 1024];
  __shared__ float rinvS[16];
  const int tid = threadIdx.x;
  const int i0 = blockIdx.x * 16;
  const int h = blockIdx.y, b = blockIdx.z;
  const int g = h >> 3;
  const size_t bg = (size_t)(b * 2 + g);
  const int r = tid >> 4, li = tid & 15;
  const __bf16* Trow = Tg + bg * 1048576 + (size_t)(i0 + r) * 1024;
  const __bf16* Mrow = Mh + (size_t)h * 1048576 + (size_t)(i0 + r) * 1024;

  // single pass: s = t*m, e = exp(s), sum, store swizzled 16B
  float sum = 0.f;
#pragma unroll
  for (int q = 0; q < 8; ++q) {
    const int jb = q * 128 + li * 8;
    const bf16x8 t8 = *(const bf16x8*)&Trow[jb];
    const bf16x8 m8 = *(const bf16x8*)&Mrow[jb];
    const int c = jb >> 3;                     // chunk index
    const int csw = c ^ (r & 7);
    bf16x8 p8;
#pragma unroll
    for (int k = 0; k < 8; ++k) {
      const float e = __expf((float)t8[k] * (float)m8[k]);
      sum += e;
      p8[k] = (__bf16)e;
    }
    *(bf16x8*)&P[r * 1024 + csw * 8] = p8;
  }
  sum += __shfl_xor(sum, 1);
  sum += __shfl_xor(sum, 2);
  sum += __shfl_xor(sum, 4);
  sum += __shfl_xor(sum, 8);
  if (li == 0) rinvS[r] = 1.f / sum;
  __syncthreads();

  // PV: wave wv covers d in [wv*16, wv*16+16)
  const int lane = tid & 63, wv = tid >> 6;
  const int m = lane & 15, kq = lane >> 4;
  const __bf16* vbase = Vt + ((size_t)(b * 16 + h) * 64 + wv * 16 + m) * 1024 + kq * 8;
  f32x4 acc = (f32x4){0.f, 0.f, 0.f, 0.f};
#pragma unroll 8
  for (int ks = 0; ks < 32; ++ks) {
    const int c = ks * 4 + kq;
    const bf16x8 a = *(const bf16x8*)&P[m * 1024 + ((c ^ (m & 7)) << 3)];
    const bf16x8 vv = *(const bf16x8*)&vbase[ks * 32];
    acc = __builtin_amdgcn_mfma_f32_16x16x32_bf16(a, vv, acc, 0, 0, 0);
  }
#pragma unroll
  for (int reg = 0; reg < 4; ++reg) {
    const int row = kq * 4 + reg;
    av[((size_t)(i0 + row) * 4 + b) * 1024 + h * 64 + wv * 16 + m] =
        (__bf16)(acc[reg] * rinvS[row]);
  }
}

// ---------------------------------------------------------------------------
// residual + LayerNorm
// ---------------------------------------------------------------------------
__global__ __launch_bounds__(256) void ln_kernel(
    const float* __restrict__ w, const float* __restrict__ ao,
    const float* __restrict__ gamma, const float* __restrict__ beta,
    float* __restrict__ out)
{
  const int tid = threadIdx.x;
  const size_t base = (size_t)blockIdx.x * DMODEL;
  __shared__ float red[256];
  float x[4];
  float s = 0.f;
#pragma unroll
  for (int p = 0; p < 4; ++p) {
    const int c = tid + p * 256;
    x[p] = w[base + c] + ao[base + c];
    s += x[p];
  }
  red[tid] = s; __syncthreads();
  for (int off = 128; off > 0; off >>= 1) {
    if (tid < off) red[tid] += red[tid + off];
    __syncthreads();
  }
  const float mu = red[0] * (1.f / DMODEL);
  __syncthreads();
  float s2 = 0.f;
#pragma unroll
  for (int p = 0; p < 4; ++p) { const float t = x[p] - mu; s2 += t * t; }
  red[tid] = s2; __syncthreads();
  for (int off = 128; off > 0; off >>= 1) {
    if (tid < off) red[tid] += red[tid + off];
    __syncthreads();
  }
  const float rs = rsqrtf(red[0] * (1.f / DMODEL) + LN_EPS);
#pragma unroll
  for (int p = 0; p < 4; ++p) {
    const int c = tid + p * 256;
    out[base + c] = (x[p] - mu) * rs * gamma[c] + beta[c];
  }
}

// ---------------------------------------------------------------------------
extern "C" void kernel_launch(void* const* d_in, const int* in_sizes, int n_in,
                              void* d_out, int out_size, void* d_ws, size_t ws_size,
                              hipStream_t stream)
{
  const float* w     = (const float*)d_in[0];
  const float* r     = (const float*)d_in[1];
  const float* rwb   = (const float*)d_in[2];
  const float* rrb   = (const float*)d_in[3];
  const float* masks = (const float*)d_in[4];
  const float* Wqkv  = (const float*)d_in[5];
  const float* Wr    = (const float*)d_in[6];
  const float* mproj = (const float*)d_in[7];
  const float* Wo    = (const float*)d_in[8];
  const float* gam   = (const float*)d_in[9];
  const float* bet   = (const float*)d_in[10];
  float* out = (float*)d_out;

  float* ws = (float*)d_ws;
  // fp32-unit offsets (footprint 26,279,936 f = 105.1 MB, same as before)
  __bf16* wh_bf   = (__bf16*)(ws);                   // [4096][1280]
  __bf16* rk_bf   = (__bf16*)(ws + 2621440);         // [1024][128]
  __bf16* Qw      = (__bf16*)(ws + 2686976);
  __bf16* Qr      = (__bf16*)(ws + 2949120);
  __bf16* Kb      = (__bf16*)(ws + 3211264);
  __bf16* Rb      = (__bf16*)(ws + 3473408);
  __bf16* AC_bf   = (__bf16*)(ws + 3735552);         // [8][1024][1024]
  __bf16* BD_bf   = (__bf16*)(ws + 7929856);         // [8][1024][1024]
  __bf16* Tg      = (__bf16*)(ws + 12124160);        // [8][1024][1024]
  __bf16* Wo_bf   = (__bf16*)(ws + 16318464);        // [1024][1024] (old masksP slot)
  __bf16* Vt      = (__bf16*)(ws + 17891328);        // [64][64][1024]
  __bf16* av_bf   = (__bf16*)(ws + 19988480);        // [4096][1024]
  float*  ao      = ws + 22085632;                   // [4096][1024] fp32
  // overlays:
  __bf16* w_bf    = (__bf16*)(ws + 3735552);         // AC region, pre-gemm64
  __bf16* Wqkv_bf = (__bf16*)(ws + 5832704);         // AC region, pre-gemm64
  __bf16* r_bf    = (__bf16*)(ws + 6488064);         // AC region, pre-gemm64
  __bf16* Wr_bf   = (__bf16*)(ws + 7012352);         // AC region, pre-gemm64
  __bf16* Mh      = (__bf16*)(ws);                   // 16x[1024][1024], post-tshift
                                                     // (overlays wh/rk/Q*/AC/BD-head, all dead)

  // 1) all input casts (one dispatch)
  cast_all<<<3776, 256, 0, stream>>>(w, w_bf, Wqkv, Wqkv_bf, r, r_bf,
                                     Wr, Wr_bf, Wo, Wo_bf);
  // 2) QKV projection -> bf16 wh
  gemm_bf16<__bf16><<<dim3(10, 32), 256, 0, stream>>>(
      w_bf, Wqkv_bf, wh_bf, 1024, 1024, 1024, 1280);
  // 3) r projection -> bf16 rk
  gemm_bf16<__bf16><<<dim3(1, 8), 256, 0, stream>>>(
      r_bf, Wr_bf, rk_bf, 1024, 1024, 1024, 128);
  // 4) V transpose, Q/K/R prep
  vt_cast<<<dim3(16, 64), 256, 0, stream>>>(wh_bf, Vt);
  qkr_prep<<<dim3(64, 8), 256, 0, stream>>>(wh_bf, rk_bf, rwb, rrb, Qw, Qr, Kb, Rb);
  // 5) AC/BD via MFMA
  gemm64_bf16<<<dim3(8, 8, 16), 256, 0, stream>>>(Qw, Qr, Kb, Rb, AC_bf, BD_bf);
  // 6) rel-shift fold: T = (AC + BDshift) * SCALE
  tshift<<<2048, 256, 0, stream>>>(AC_bf, BD_bf, Tg);
  // 7) per-head mixed masks (overlays dead wh/Q*/AC regions)
  mh_prep<<<1024, 256, 0, stream>>>(masks, mproj, Mh);
  // 8) attention: scores + softmax + PV
  attn4<<<dim3(64, 16, 4), 256, 0, stream>>>(Tg, Mh, Vt, av_bf);
  // 9) output projection -> fp32 ao
  gemm_bf16<float><<<dim3(8, 32), 256, 0, stream>>>(
      av_bf, Wo_bf, ao, 1024, 1024, 1024, 1024);
  // 10) residual + LayerNorm
  ln_kernel<<<4096, 256, 0, stream>>>(w, ao, gam, bet, out);
}